// Round 12
// baseline (383.153 us; speedup 1.0000x reference)
//
#include <hip/hip_runtime.h>
#include <math.h>

// ---------------------------------------------------------------------------
// HGT layer slice. R23: kq via f16x2-split MFMA (fp32-grade on matrix pipe).
// R22 post-mortem: attend fixed (out of top-5); kq_f32 leads at 62.4us,
// stuck at 3x its 21us issue floor across R17-R20 — fp32 vector FMA is the
// structural ceiling (no fp32 MFMA on CDNA4). Fix: x = hi + lo (hi=f16(x),
// lo=f16(x-hi), exact split, 22-bit combined mantissa); h@W = hiWhi + hiWlo
// + loWhi via 3 f16 MFMA passes, f32 accumulate (f16 products exact in
// f32). Error ~1e-6 relative — 500x finer than the already-accepted f16
// output rounding; 1e-6-level score ties that could flip argmax have
// near-equal exp weights -> benign (unlike R6's 1e-3 f16-input failure).
// Kernel structure cloned from the VERIFIED vproj MFMA kernel.
// Workspace (stream-order audit): hLo@28.8M wds (=VMF[1], dead before
// nrg2), W-splits@48.0-48.3M (=VMF[7], dead before nrg2), hHi == hF.
//
// attend v4 (R22), nr_gemm v6 (R16), online softmax (R21), parallel scan
// (R10), [rel][node] layout (R12).
// ---------------------------------------------------------------------------

#define N_NODES 50000
#define N_EDGES 500000
#define DIM 128
#define TT 8
#define RR 8
#define RSQRT_DK 0.08838834764831845f

#define CHUNK_GRID 399               // 399*128 = 51072 >= 50000 + 8*127
#define NODE_LIST_LEN (CHUNK_GRID * 128)
#define GRID_E ((N_EDGES + 255) / 256)   // 1954, also covers N
#define SCAN_BLOCKS ((N_NODES + 255) / 256)   // 196

// nr_gemm v6 geometry: 112 chunks x 448 rows (7 iters x 64) = 50176 >= 50000
// 112 % 8 == 0 -> blocks rel*112+c land on xcd = c%8 for every rel.
#define NR3_CHUNKS 112
#define NR3_ROWS 448
#define NR3_ITERS 7

// word offsets (4B units); _Float16 index = 2*word
// Lifetime audit (stream order: kq_mfma -> vproj -> nrg1(KA) -> nrg2(VM) ->
// attend -> out):
//   KA  @ 0..25.6M    written by nrg1; hF alias dead after vproj
//   VMF @ 25.6..51.2M written by nrg2; kF/hLo/Wsplit aliases dead by then
//   kF  @ 25.6M       written by kq_mfma, read by nrg1, clobbered by nrg2 OK
//   hLo @ 28.8M       (=VMF[1]) written by hconv, read by kq_mfma, dead
//   Wsplit@48.0-48.3M (=VMF[7]) written by convert2, read by kq_mfma, dead
//   qF  @ 51.2M       written by kq_mfma, read by attend; no aliasing writer
//   aggF@ 54.4M       written by attend, read by out; vF alias dead by then
#define OFF_KA 0                   // kA f16 [rel][n][128]
#define OFF_HF 0                   // alias: hF16 = hHi (dead before KA write)
#define OFF_VM 25600000            // VMF16 [rel][n][128]
#define OFF_KF 25600000            // alias: kF16 (dead before VM write)
#define OFF_HLO 28800000           // hLo f16 [n][128] (=VMF[1] region)
#define OFF_WKHI 48000000          // W f16x2 splits, [t][f][d], 100k spacing
#define OFF_WKLO 48100000          //   (=VMF[7] region, dead before nrg2)
#define OFF_WQHI 48200000
#define OFF_WQLO 48300000
#define OFF_QF 51200000            // qF16 — no aliasing writer after kq
#define OFF_AGGF 54400000
#define OFF_VF 54400000            // alias: vF16 (dead before attend writes agg)
#define OFF_ATTT 57600000          // attT [r][f][d] (transposed), 100k spacing
#define OFF_MSGT 57700000
#define OFF_WVT 57800000
#define OFF_WAT 57900000
#define OFF_INT 58000000           // int region, +701,872 -> 58,701,872 words
#define IO_NLIST 0                 // 51,072
#define IO_CNT_N 51072
#define IO_CUR_N 51080
#define IO_POFF_N 51088
#define IO_DCNT 51104              // 50,000
#define IO_DCUR 101104             // 50,000
#define IO_DOFF 151104             // 50,000
#define IO_DPR 201104              // 500,000 packed (src*8|rel) per CSR slot
#define IO_BLKSUM 701104           // 256 per-scan-block totals
#define IO_BLKOFF 701360           // 256 scanned block offsets; end 701,616

typedef _Float16 half8 __attribute__((ext_vector_type(8)));
typedef _Float16 half4 __attribute__((ext_vector_type(4)));
typedef float f32x4 __attribute__((ext_vector_type(4)));

__global__ void init_kernel(int* wsi) {
    int i = blockIdx.x * blockDim.x + threadIdx.x;
    if (i < NODE_LIST_LEN) wsi[IO_NLIST + i] = -1;
    if (i < 32) wsi[IO_CNT_N + i] = 0;
    if (i < 100000) wsi[IO_DCNT + i] = 0;  // dcnt + dcur contiguous
}

// weight tensors transposed to [.][f][d] f16
__global__ void convert_kernel(const float* __restrict__ att,
                               const float* __restrict__ msg,
                               const float* __restrict__ Wv,
                               const float* __restrict__ Wa,
                               _Float16* __restrict__ attT,
                               _Float16* __restrict__ msgT,
                               _Float16* __restrict__ WvT,
                               _Float16* __restrict__ WaT) {
    int i = blockIdx.x * 256 + threadIdx.x;
    if (i >= RR * DIM * DIM) return;
    int td = i >> 14, d = (i >> 7) & 127, f = i & 127;
    int tr = (td << 14) + (f << 7) + d;
    attT[tr] = (_Float16)att[i];
    msgT[tr] = (_Float16)msg[i];
    WvT[tr] = (_Float16)Wv[i];
    WaT[tr] = (_Float16)Wa[i];
}

// f16x2 split of Wk, Wq (transposed [t][f][d]): hi = f16(x), lo = f16(x-hi)
__global__ void convert2_kernel(const float* __restrict__ Wk,
                                const float* __restrict__ Wq,
                                _Float16* __restrict__ WkHiT,
                                _Float16* __restrict__ WkLoT,
                                _Float16* __restrict__ WqHiT,
                                _Float16* __restrict__ WqLoT) {
    int i = blockIdx.x * 256 + threadIdx.x;
    if (i >= TT * DIM * DIM) return;
    int td = i >> 14, d = (i >> 7) & 127, f = i & 127;
    int tr = (td << 14) + (f << 7) + d;
    float xk = Wk[i];
    _Float16 hk = (_Float16)xk;
    WkHiT[tr] = hk;
    WkLoT[tr] = (_Float16)(xk - (float)hk);  // Sterbenz: exact subtraction
    float xq = Wq[i];
    _Float16 hq = (_Float16)xq;
    WqHiT[tr] = hq;
    WqLoT[tr] = (_Float16)(xq - (float)hq);
}

// h -> hF (hi) + hLo (residual), both f16
__global__ void hconv_kernel(const float* __restrict__ h,
                             _Float16* __restrict__ hF,
                             _Float16* __restrict__ hLo) {
    int i = blockIdx.x * 256 + threadIdx.x;
    if (i < N_NODES * DIM / 4) {
        float4 v = ((const float4*)h)[i];
        half4 o, r;
        o[0] = (_Float16)v.x; o[1] = (_Float16)v.y;
        o[2] = (_Float16)v.z; o[3] = (_Float16)v.w;
        r[0] = (_Float16)(v.x - (float)o[0]);
        r[1] = (_Float16)(v.y - (float)o[1]);
        r[2] = (_Float16)(v.z - (float)o[2]);
        r[3] = (_Float16)(v.w - (float)o[3]);
        *(half4*)(hF + (size_t)i * 4) = o;
        *(half4*)(hLo + (size_t)i * 4) = r;
    }
}

__global__ void hist_kernel(const int* __restrict__ ntype,
                            const int* __restrict__ adj, int* wsi) {
    __shared__ int cn[TT];
    int tid = threadIdx.x;
    if (tid < TT) cn[tid] = 0;
    __syncthreads();
    int i = blockIdx.x * blockDim.x + tid;
    if (i < N_NODES) atomicAdd(&cn[ntype[i]], 1);
    if (i < N_EDGES) atomicAdd(&wsi[IO_DCNT + adj[N_EDGES + i]], 1);
    __syncthreads();
    if (tid < TT && cn[tid] > 0) atomicAdd(&wsi[IO_CNT_N + tid], cn[tid]);
}

__global__ void offsets_kernel(int* wsi) {
    int off = 0;
    for (int t = 0; t < TT; ++t) {
        wsi[IO_POFF_N + t] = off;
        off += ((wsi[IO_CNT_N + t] + 127) >> 7) << 7;  // pad to 128
    }
}

// 3-phase parallel exclusive scan of the 50k dst counts
__global__ __launch_bounds__(256) void scanA_kernel(int* wsi) {
    __shared__ int tmp[256];
    int tid = threadIdx.x;
    int i = blockIdx.x * 256 + tid;
    int v = (i < N_NODES) ? wsi[IO_DCNT + i] : 0;
    tmp[tid] = v;
    __syncthreads();
    for (int off = 1; off < 256; off <<= 1) {
        int t = (tid >= off) ? tmp[tid - off] : 0;
        __syncthreads();
        tmp[tid] += t;
        __syncthreads();
    }
    if (i < N_NODES) wsi[IO_DOFF + i] = tmp[tid] - v;  // block-local exclusive
    if (tid == 255) wsi[IO_BLKSUM + blockIdx.x] = tmp[255];
}

__global__ __launch_bounds__(256) void scanB_kernel(int* wsi) {
    __shared__ int tmp[256];
    int tid = threadIdx.x;
    int v = (tid < SCAN_BLOCKS) ? wsi[IO_BLKSUM + tid] : 0;
    tmp[tid] = v;
    __syncthreads();
    for (int off = 1; off < 256; off <<= 1) {
        int t = (tid >= off) ? tmp[tid - off] : 0;
        __syncthreads();
        tmp[tid] += t;
        __syncthreads();
    }
    wsi[IO_BLKOFF + tid] = tmp[tid] - v;
}

__global__ __launch_bounds__(256) void scanC_kernel(int* wsi) {
    int i = blockIdx.x * 256 + threadIdx.x;
    if (i < N_NODES) wsi[IO_DOFF + i] += wsi[IO_BLKOFF + blockIdx.x];
}

__global__ void scatter_kernel(const int* __restrict__ ntype,
                               const int* __restrict__ etype,
                               const int* __restrict__ adj, int* wsi) {
    __shared__ int cn[TT], bn[TT];
    int tid = threadIdx.x;
    if (tid < TT) cn[tid] = 0;
    __syncthreads();
    int i = blockIdx.x * blockDim.x + tid;
    int t = -1, rnk = 0;
    if (i < N_NODES) {
        t = ntype[i];
        rnk = atomicAdd(&cn[t], 1);
    }
    __syncthreads();
    if (tid < TT && cn[tid] > 0) bn[tid] = atomicAdd(&wsi[IO_CUR_N + tid], cn[tid]);
    __syncthreads();
    if (t >= 0)
        wsi[IO_NLIST + wsi[IO_POFF_N + t] + bn[t] + rnk] = i;
    if (i < N_EDGES) {
        int d = adj[N_EDGES + i];
        int pos = wsi[IO_DOFF + d] + atomicAdd(&wsi[IO_DCUR + d], 1);
        wsi[IO_DPR + pos] = (adj[i] << 3) | etype[i];  // packed src*8|rel
    }
}

// ---------------------------------------------------------------------------
// kq via f16x2-split MFMA (R23): structure cloned from the verified vproj
// kernel. acc = hHi@WHi + hHi@WLo + hLo@WHi, f32 accumulate; ~1e-6 relative
// error vs the fp32 GEMM (<< f16 output rounding). blockIdx.y = w (k/q).
// ---------------------------------------------------------------------------
__global__ __launch_bounds__(256) void kq_mfma_kernel(
    const _Float16* __restrict__ hHi, const _Float16* __restrict__ hLo,
    const int* __restrict__ ntype,
    const _Float16* __restrict__ WkHiT, const _Float16* __restrict__ WkLoT,
    const _Float16* __restrict__ WqHiT, const _Float16* __restrict__ WqLoT,
    const int* __restrict__ nlist, _Float16* __restrict__ kout,
    _Float16* __restrict__ qout) {
    __shared__ int nid[128];
    int tid = threadIdx.x;
    if (tid < 128) nid[tid] = nlist[blockIdx.x * 128 + tid];
    __syncthreads();
    if (nid[0] < 0) return;
    int t = ntype[nid[0]];
    int wv = tid >> 6, lane = tid & 63, l16 = lane & 15, quad = lane >> 4;
    int r0 = wv * 32;
    int nA[2];
#pragma unroll
    for (int m = 0; m < 2; ++m) nA[m] = nid[r0 + m * 16 + l16];
    int w = blockIdx.y;
    const _Float16* BHi = (w ? WqHiT : WkHiT) + (t << 14);
    const _Float16* BLo = (w ? WqLoT : WkLoT) + (t << 14);
    _Float16* O = w ? qout : kout;
    f32x4 acc[2][8];
#pragma unroll
    for (int m = 0; m < 2; ++m)
#pragma unroll
        for (int c = 0; c < 8; ++c) acc[m][c] = (f32x4){0.f, 0.f, 0.f, 0.f};
    for (int kk = 0; kk < 4; ++kk) {
        int kb = kk * 32 + quad * 8;
        half8 aHi[2], aLo[2];
#pragma unroll
        for (int m = 0; m < 2; ++m) {
            aHi[m] = (nA[m] >= 0)
                         ? *(const half8*)(hHi + (size_t)nA[m] * DIM + kb)
                         : (half8){0, 0, 0, 0, 0, 0, 0, 0};
            aLo[m] = (nA[m] >= 0)
                         ? *(const half8*)(hLo + (size_t)nA[m] * DIM + kb)
                         : (half8){0, 0, 0, 0, 0, 0, 0, 0};
        }
#pragma unroll
        for (int c = 0; c < 8; ++c) {
            half8 bHi = *(const half8*)(BHi + (c * 16 + l16) * DIM + kb);
            half8 bLo = *(const half8*)(BLo + (c * 16 + l16) * DIM + kb);
#pragma unroll
            for (int m = 0; m < 2; ++m) {
                acc[m][c] = __builtin_amdgcn_mfma_f32_16x16x32_f16(
                    aHi[m], bHi, acc[m][c], 0, 0, 0);
                acc[m][c] = __builtin_amdgcn_mfma_f32_16x16x32_f16(
                    aHi[m], bLo, acc[m][c], 0, 0, 0);
                acc[m][c] = __builtin_amdgcn_mfma_f32_16x16x32_f16(
                    aLo[m], bHi, acc[m][c], 0, 0, 0);
            }
        }
    }
#pragma unroll
    for (int m = 0; m < 2; ++m)
#pragma unroll
        for (int c = 0; c < 8; ++c)
#pragma unroll
            for (int rg = 0; rg < 4; ++rg) {
                int node = nid[r0 + m * 16 + quad * 4 + rg];
                if (node >= 0)
                    O[(size_t)node * DIM + c * 16 + l16] =
                        (_Float16)acc[m][c][rg];
            }
}

// v: 128-node type-uniform chunk MFMA GEMM (value path: f16-tolerant)
__global__ __launch_bounds__(256) void vproj_kernel(
    const _Float16* __restrict__ hF, const int* __restrict__ ntype,
    const _Float16* __restrict__ WvT, const int* __restrict__ nlist,
    _Float16* __restrict__ vout) {
    __shared__ int nid[128];
    int tid = threadIdx.x;
    if (tid < 128) nid[tid] = nlist[blockIdx.x * 128 + tid];
    __syncthreads();
    if (nid[0] < 0) return;
    int t = ntype[nid[0]];
    int wv = tid >> 6, lane = tid & 63, l16 = lane & 15, quad = lane >> 4;
    int r0 = wv * 32;
    int nA[2];
#pragma unroll
    for (int m = 0; m < 2; ++m) nA[m] = nid[r0 + m * 16 + l16];
    const _Float16* B = WvT + (t << 14);
    f32x4 acc[2][8];
#pragma unroll
    for (int m = 0; m < 2; ++m)
#pragma unroll
        for (int c = 0; c < 8; ++c) acc[m][c] = (f32x4){0.f, 0.f, 0.f, 0.f};
    for (int kk = 0; kk < 4; ++kk) {
        int kb = kk * 32 + quad * 8;
        half8 a[2];
#pragma unroll
        for (int m = 0; m < 2; ++m)
            a[m] = (nA[m] >= 0)
                       ? *(const half8*)(hF + (size_t)nA[m] * DIM + kb)
                       : (half8){0, 0, 0, 0, 0, 0, 0, 0};
#pragma unroll
        for (int c = 0; c < 8; ++c) {
            half8 b = *(const half8*)(B + (c * 16 + l16) * DIM + kb);
#pragma unroll
            for (int m = 0; m < 2; ++m)
                acc[m][c] = __builtin_amdgcn_mfma_f32_16x16x32_f16(
                    a[m], b, acc[m][c], 0, 0, 0);
        }
    }
#pragma unroll
    for (int m = 0; m < 2; ++m)
#pragma unroll
        for (int c = 0; c < 8; ++c)
#pragma unroll
            for (int rg = 0; rg < 4; ++rg) {
                int node = nid[r0 + m * 16 + quad * 4 + rg];
                if (node >= 0)
                    vout[(size_t)node * DIM + c * 16 + l16] =
                        (_Float16)acc[m][c][rg];
            }
}

// ---------------------------------------------------------------------------
// nr_gemm v6 (R16-proven): one block = one rel; B register-resident; stream
// NR3_ITERS x 64-row tiles with double-buffered A prefetch.
// Pass 1: Out=KA, A=kF, B=attT, scale=pri*rsqrt. Pass 2: Out=VMF, A=vF,
// B=msgT, scale=1.
// ---------------------------------------------------------------------------
__global__ __launch_bounds__(256, 2) void nr_gemm3_kernel(
    const _Float16* __restrict__ A, const _Float16* __restrict__ B8,
    _Float16* __restrict__ Out, const float* __restrict__ pri, int isU) {
    __shared__ _Float16 stage[4][16][136];
    int bid = blockIdx.x;
    int rel = bid / NR3_CHUNKS;
    int chunk = bid - rel * NR3_CHUNKS;
    float scale = isU ? pri[rel] * RSQRT_DK : 1.0f;
    const _Float16* Bb = B8 + (rel << 14);
    int tid = threadIdx.x;
    int wv = tid >> 6, lane = tid & 63;
    int l16 = lane & 15, quad = lane >> 4;

    // B fragments once: bfrag[c][kk] covers B-row c*16+l16, k=kk*32+quad*8
    half8 bfrag[8][4];
#pragma unroll
    for (int c = 0; c < 8; ++c)
#pragma unroll
        for (int kk = 0; kk < 4; ++kk)
            bfrag[c][kk] =
                *(const half8*)(Bb + (c * 16 + l16) * DIM + kk * 32 + quad * 8);

    _Float16* Orel = Out + (size_t)rel * N_NODES * DIM;
    int base = chunk * NR3_ROWS + wv * 16;  // this wave's first tile row

    // prefetch tile 0
    half8 aNow[4], aNext[4];
    {
        int nodeA = base + l16;
#pragma unroll
        for (int kk = 0; kk < 4; ++kk)
            aNow[kk] = (nodeA < N_NODES)
                           ? *(const half8*)(A + (size_t)nodeA * DIM +
                                             kk * 32 + quad * 8)
                           : (half8){0, 0, 0, 0, 0, 0, 0, 0};
    }

    for (int it = 0; it < NR3_ITERS; ++it) {
        int row0 = base + it * 64;
        // prefetch next tile's A while this tile computes
        if (it + 1 < NR3_ITERS) {
            int nodeA = row0 + 64 + l16;
#pragma unroll
            for (int kk = 0; kk < 4; ++kk)
                aNext[kk] = (nodeA < N_NODES)
                                ? *(const half8*)(A + (size_t)nodeA * DIM +
                                                  kk * 32 + quad * 8)
                                : (half8){0, 0, 0, 0, 0, 0, 0, 0};
        }
        f32x4 acc[8];
#pragma unroll
        for (int c = 0; c < 8; ++c) acc[c] = (f32x4){0.f, 0.f, 0.f, 0.f};
#pragma unroll
        for (int kk = 0; kk < 4; ++kk)
#pragma unroll
            for (int c = 0; c < 8; ++c)
                acc[c] = __builtin_amdgcn_mfma_f32_16x16x32_f16(
                    bfrag[c][kk], aNow[kk], acc[c], 0, 0, 0);
        // stage transposed acc into wave-private LDS: row = local node l16,
        // feature = c*16 + quad*4 + rg
#pragma unroll
        for (int c = 0; c < 8; ++c) {
            half4 o;
#pragma unroll
            for (int rg = 0; rg < 4; ++rg)
                o[rg] = (_Float16)(acc[c][rg] * scale);
            *(half4*)&stage[wv][l16][c * 16 + quad * 4] = o;
        }
        // read back row-wise: 4 x (4 rows x 256B) = 1KiB contiguous stores
        _Float16* Op = Orel + (size_t)row0 * DIM;
#pragma unroll
        for (int s = 0; s < 4; ++s) {
            int row = s * 4 + quad;
            if (row0 + row < N_NODES) {
                half8 v = *(const half8*)&stage[wv][row][l16 * 8];
                *(half8*)(Op + (size_t)row * DIM + l16 * 8) = v;
            }
        }
#pragma unroll
        for (int kk = 0; kk < 4; ++kk) aNow[kk] = aNext[kk];
    }
}

// ---------------------------------------------------------------------------
// attend v4 (R22): score = kA[rel][src] . q[dst]. One gather per edge in
// phase 1; q[dst] register-resident; online per-rel softmax (R21); no LDS.
// ---------------------------------------------------------------------------
__global__ __launch_bounds__(256) void attend_kernel(
    const _Float16* __restrict__ KA, const _Float16* __restrict__ qF,
    const _Float16* __restrict__ VMF, const int* __restrict__ dpr,
    const int* __restrict__ doff, const int* __restrict__ dcnt,
    _Float16* __restrict__ aggF) {
    int wv = threadIdx.x >> 6, lane = threadIdx.x & 63;
    int dst = blockIdx.x * 4 + wv;
    if (dst >= N_NODES) return;
    int l16 = lane & 15, g = lane >> 4, l8 = lane & 7;
    int beg = doff[dst], cnt = dcnt[dst];

    // q[dst] fragment: 8 halves per lane, register-resident for the kernel
    half8 qv = *(const half8*)(qF + (size_t)dst * DIM + l16 * 8);

    float m_own = -3e38f, sum_own = 0.f;
    float s0 = 0.f, s1 = 0.f, s2 = 0.f;
    int p0 = 0, p1 = 0, p2 = 0;

    // phase 1: scores; park (s, pr); ONLINE per-rel (max, sum) on owning lane
    for (int j0 = 0; j0 < cnt; j0 += 4) {
        int j = j0 + g;
        bool valid = j < cnt;
        int pr = valid ? dpr[beg + j] : 0;
        int src = pr >> 3, rel = pr & 7;
        half8 kv = *(const half8*)(KA + ((size_t)rel * N_NODES + src) * DIM +
                                   l16 * 8);
        float sa = 0.f, sb = 0.f;
#pragma unroll
        for (int i = 0; i < 4; ++i) sa += (float)kv[i] * (float)qv[i];
#pragma unroll
        for (int i = 4; i < 8; ++i) sb += (float)kv[i] * (float)qv[i];
        float s = sa + sb;
        s += __shfl_xor(s, 1, 16);
        s += __shfl_xor(s, 2, 16);
        s += __shfl_xor(s, 4, 16);
        s += __shfl_xor(s, 8, 16);
        if (!valid) s = -3e38f;
        int slot = j0 >> 6;            // wave-uniform
        int idx = (j0 >> 2) & 15;      // wave-uniform
        if (l16 == idx) {
            if (slot == 0) { s0 = s; p0 = pr; }
            else if (slot == 1) { s1 = s; p1 = pr; }
            else if (slot == 2) { s2 = s; p2 = pr; }
        }
        if (valid && l8 == rel) {
            if (s > m_own) {
                sum_own *= __expf(m_own - s);  // 0 * exp(-huge) = 0 first time
                m_own = s;
            }
            sum_own += __expf(s - m_own);
        }
    }
    // joint merge of (m, sum) across the 4 groups (exp-rescale combine)
    {
        float m2 = __shfl_xor(m_own, 16, 64);
        float t2 = __shfl_xor(sum_own, 16, 64);
        float mn = fmaxf(m_own, m2);
        sum_own = sum_own * __expf(m_own - mn) + t2 * __expf(m2 - mn);
        m_own = mn;
        m2 = __shfl_xor(m_own, 32, 64);
        t2 = __shfl_xor(sum_own, 32, 64);
        mn = fmaxf(m_own, m2);
        sum_own = sum_own * __expf(m_own - mn) + t2 * __expf(m2 - mn);
        m_own = mn;
    }
    float inv_own = (sum_own > 0.f) ? 1.f / sum_own : 0.f;

    // phase 2: alpha = exp(s - m[rel]) * inv[rel]; acc += alpha * VM[rel][src]
    float acc[8] = {0.f, 0.f, 0.f, 0.f, 0.f, 0.f, 0.f, 0.f};
    for (int j0 = 0; j0 < cnt; j0 += 4) {
        int j = j0 + g;
        bool valid = j < cnt;
        int slot = j0 >> 6;
        int idx = (j0 >> 2) & 15;
        float s;
        int pr;
        if (slot < 3) {
            float sv = (slot == 0) ? s0 : (slot == 1) ? s1 : s2;
            int pv = (slot == 0) ? p0 : (slot == 1) ? p1 : p2;
            s = __shfl(sv, idx, 16);
            pr = __shfl(pv, idx, 16);
        } else {  // overflow fallback: recompute (cnt>192 ~ never at deg~10)
            pr = valid ? dpr[beg + j] : 0;
            int src = pr >> 3, rel = pr & 7;
            half8 kv = *(const half8*)(KA +
                                       ((size_t)rel * N_NODES + src) * DIM +
                                       l16 * 8);
            float sa = 0.f, sb = 0.f;
#pragma unroll
            for (int i = 0; i < 4; ++i) sa += (float)kv[i] * (float)qv[i];
#pragma unroll
            for (int i = 4; i < 8; ++i) sb += (float)kv[i] * (float)qv[i];
            s = sa + sb;
            s += __shfl_xor(s, 1, 16);
            s += __shfl_xor(s, 2, 16);
            s += __shfl_xor(s, 4, 16);
            s += __shfl_xor(s, 8, 16);
        }
        int rel = pr & 7, src = pr >> 3;
        float mr = __shfl(m_own, rel, 8);
        float iv = __shfl(inv_own, rel, 8);
        float alpha = valid ? __expf(s - mr) * iv : 0.f;
        half8 v = *(const half8*)(VMF + ((size_t)rel * N_NODES + src) * DIM +
                                  l16 * 8);
#pragma unroll
        for (int i = 0; i < 8; ++i) acc[i] += alpha * (float)v[i];
    }
    // merge acc across the 4 groups (each covers the full 128 dims)
#pragma unroll
    for (int i = 0; i < 8; ++i) {
        acc[i] += __shfl_xor(acc[i], 16, 64);
        acc[i] += __shfl_xor(acc[i], 32, 64);
    }
    if (g == 0) {
        half8 o;
#pragma unroll
        for (int i = 0; i < 8; ++i) o[i] = (_Float16)acc[i];
        *(half8*)(aggF + (size_t)dst * DIM + l16 * 8) = o;
    }
}

// out: 128-node type-uniform chunk MFMA GEMM, fp32 stores with sigmoid gate
__global__ __launch_bounds__(256) void out_kernel(
    const _Float16* __restrict__ aggF, const int* __restrict__ ntype,
    const _Float16* __restrict__ WaT, const float* __restrict__ skip,
    const int* __restrict__ nlist, float* __restrict__ out) {
    __shared__ int nid[128];
    int tid = threadIdx.x;
    if (tid < 128) nid[tid] = nlist[blockIdx.x * 128 + tid];
    __syncthreads();
    if (nid[0] < 0) return;
    int t = ntype[nid[0]];
    float sig = 1.f / (1.f + __expf(-skip[t]));
    int wv = tid >> 6, lane = tid & 63, l16 = lane & 15, quad = lane >> 4;
    int r0 = wv * 32;
    int nA[2];
#pragma unroll
    for (int m = 0; m < 2; ++m) nA[m] = nid[r0 + m * 16 + l16];
    const _Float16* B = WaT + (t << 14);
    f32x4 acc[2][8];
#pragma unroll
    for (int m = 0; m < 2; ++m)
#pragma unroll
        for (int c = 0; c < 8; ++c) acc[m][c] = (f32x4){0.f, 0.f, 0.f, 0.f};
    for (int kk = 0; kk < 4; ++kk) {
        int kb = kk * 32 + quad * 8;
        half8 a[2];
#pragma unroll
        for (int m = 0; m < 2; ++m)
            a[m] = (nA[m] >= 0)
                       ? *(const half8*)(aggF + (size_t)nA[m] * DIM + kb)
                       : (half8){0, 0, 0, 0, 0, 0, 0, 0};
#pragma unroll
        for (int c = 0; c < 8; ++c) {
            half8 b = *(const half8*)(B + (c * 16 + l16) * DIM + kb);
#pragma unroll
            for (int m = 0; m < 2; ++m)
                acc[m][c] = __builtin_amdgcn_mfma_f32_16x16x32_f16(
                    a[m], b, acc[m][c], 0, 0, 0);
        }
    }
#pragma unroll
    for (int m = 0; m < 2; ++m)
#pragma unroll
        for (int c = 0; c < 8; ++c)
#pragma unroll
            for (int rg = 0; rg < 4; ++rg) {
                int node = nid[r0 + m * 16 + quad * 4 + rg];
                if (node >= 0)
                    out[(size_t)node * DIM + c * 16 + l16] =
                        acc[m][c][rg] * sig;
            }
}

extern "C" void kernel_launch(void* const* d_in, const int* in_sizes, int n_in,
                              void* d_out, int out_size, void* d_ws,
                              size_t ws_size, hipStream_t stream) {
    const float* h = (const float*)d_in[0];
    const int* adj = (const int*)d_in[1];
    const int* etype = (const int*)d_in[2];
    const int* ntype = (const int*)d_in[3];
    const float* Wk = (const float*)d_in[6];
    const float* Wq = (const float*)d_in[7];
    const float* Wv = (const float*)d_in[8];
    const float* Wa = (const float*)d_in[9];
    const float* pri = (const float*)d_in[10];
    const float* att = (const float*)d_in[11];
    const float* msg = (const float*)d_in[12];
    const float* skip = (const float*)d_in[13];
    float* out = (float*)d_out;

    int* wsi = (int*)d_ws + OFF_INT;
    _Float16* wsh = (_Float16*)d_ws;
    _Float16* KA = wsh + (size_t)OFF_KA * 2;
    _Float16* hF = wsh + (size_t)OFF_HF * 2;
    _Float16* hLo = wsh + (size_t)OFF_HLO * 2;
    _Float16* VMF = wsh + (size_t)OFF_VM * 2;
    _Float16* kF = wsh + (size_t)OFF_KF * 2;
    _Float16* qF = wsh + (size_t)OFF_QF * 2;
    _Float16* aggF = wsh + (size_t)OFF_AGGF * 2;
    _Float16* vF = wsh + (size_t)OFF_VF * 2;
    _Float16* attT = wsh + (size_t)OFF_ATTT * 2;
    _Float16* msgT = wsh + (size_t)OFF_MSGT * 2;
    _Float16* WvT = wsh + (size_t)OFF_WVT * 2;
    _Float16* WaT = wsh + (size_t)OFF_WAT * 2;
    _Float16* WkHiT = wsh + (size_t)OFF_WKHI * 2;
    _Float16* WkLoT = wsh + (size_t)OFF_WKLO * 2;
    _Float16* WqHiT = wsh + (size_t)OFF_WQHI * 2;
    _Float16* WqLoT = wsh + (size_t)OFF_WQLO * 2;

    init_kernel<<<(100000 + 255) / 256, 256, 0, stream>>>(wsi);
    convert_kernel<<<(RR * DIM * DIM + 255) / 256, 256, 0, stream>>>(
        att, msg, Wv, Wa, attT, msgT, WvT, WaT);
    convert2_kernel<<<(TT * DIM * DIM + 255) / 256, 256, 0, stream>>>(
        Wk, Wq, WkHiT, WkLoT, WqHiT, WqLoT);
    hconv_kernel<<<(N_NODES * DIM / 4 + 255) / 256, 256, 0, stream>>>(h, hF,
                                                                      hLo);
    hist_kernel<<<GRID_E, 256, 0, stream>>>(ntype, adj, wsi);
    offsets_kernel<<<1, 1, 0, stream>>>(wsi);
    scanA_kernel<<<SCAN_BLOCKS, 256, 0, stream>>>(wsi);
    scanB_kernel<<<1, 256, 0, stream>>>(wsi);
    scanC_kernel<<<SCAN_BLOCKS, 256, 0, stream>>>(wsi);
    scatter_kernel<<<GRID_E, 256, 0, stream>>>(ntype, etype, adj, wsi);
    {
        dim3 g(CHUNK_GRID, 2);  // x: 128-node chunks, y: w (k=0, q=1)
        kq_mfma_kernel<<<g, 256, 0, stream>>>(hF, hLo, ntype, WkHiT, WkLoT,
                                              WqHiT, WqLoT, wsi + IO_NLIST,
                                              kF, qF);
    }
    vproj_kernel<<<CHUNK_GRID, 256, 0, stream>>>(hF, ntype, WvT,
                                                 wsi + IO_NLIST, vF);
    // pass 1: KA = pri*rsqrt * (kF @ attT^T); writes over hF region (dead).
    // pass 2: VMF = vF @ msgT^T; writes over kF/hLo/Wsplit regions (dead).
    nr_gemm3_kernel<<<RR * NR3_CHUNKS, 256, 0, stream>>>(kF, attT, KA, pri, 1);
    nr_gemm3_kernel<<<RR * NR3_CHUNKS, 256, 0, stream>>>(vF, msgT, VMF, pri, 0);
    attend_kernel<<<(N_NODES + 3) / 4, 256, 0, stream>>>(
        KA, qF, VMF, wsi + IO_DPR, wsi + IO_DOFF, wsi + IO_DCNT, aggF);
    out_kernel<<<CHUNK_GRID, 256, 0, stream>>>(aggF, ntype, WaT, skip,
                                               wsi + IO_NLIST, out);
}

// Round 13
// 358.946 us; speedup vs baseline: 1.0674x; 1.0674x over previous
//
#include <hip/hip_runtime.h>
#include <math.h>

// ---------------------------------------------------------------------------
// HGT layer slice. R24: kq v7 — LDS-staged B for the f16x2-split MFMA.
// R23 post-mortem: split worked (62.4->50.7us, absmax unchanged) but the
// kernel is latency-bound (MfmaUtil 7%): each of 4 waves re-loads the full
// 64KB WHi+WLo pair from L2 inside the (c,kk) loop — 4x intra-block
// redundancy, ~200cy dependent load per 6 MFMAs. Fix: stage B once per
// block into LDS (2 x [128][136] f16; 272B row stride spreads each
// ds_read_b128's 64 lane-starts evenly over the 8 16B bank slots — the
// b128 floor; 256B stride would halve throughput). B L2 traffic 204->52MB;
// MFMA feeds from ~12cy LDS instead of L2. launch_bounds(256,2).
//
// attend v4 (R22), nr_gemm v6 (R16), online softmax (R21), f16x2 split
// (R23), parallel scan (R10), [rel][node] layout (R12).
// ---------------------------------------------------------------------------

#define N_NODES 50000
#define N_EDGES 500000
#define DIM 128
#define TT 8
#define RR 8
#define RSQRT_DK 0.08838834764831845f

#define CHUNK_GRID 399               // 399*128 = 51072 >= 50000 + 8*127
#define NODE_LIST_LEN (CHUNK_GRID * 128)
#define GRID_E ((N_EDGES + 255) / 256)   // 1954, also covers N
#define SCAN_BLOCKS ((N_NODES + 255) / 256)   // 196

// nr_gemm v6 geometry: 112 chunks x 448 rows (7 iters x 64) = 50176 >= 50000
// 112 % 8 == 0 -> blocks rel*112+c land on xcd = c%8 for every rel.
#define NR3_CHUNKS 112
#define NR3_ROWS 448
#define NR3_ITERS 7

// word offsets (4B units); _Float16 index = 2*word
// Lifetime audit (stream order: kq_mfma -> vproj -> nrg1(KA) -> nrg2(VM) ->
// attend -> out):
//   KA  @ 0..25.6M    written by nrg1; hF alias dead after vproj
//   VMF @ 25.6..51.2M written by nrg2; kF/hLo/Wsplit aliases dead by then
//   kF  @ 25.6M       written by kq_mfma, read by nrg1, clobbered by nrg2 OK
//   hLo @ 28.8M       (=VMF[1]) written by hconv, read by kq_mfma, dead
//   Wsplit@48.0-48.3M (=VMF[7]) written by convert2, read by kq_mfma, dead
//   qF  @ 51.2M       written by kq_mfma, read by attend; no aliasing writer
//   aggF@ 54.4M       written by attend, read by out; vF alias dead by then
#define OFF_KA 0                   // kA f16 [rel][n][128]
#define OFF_HF 0                   // alias: hF16 = hHi (dead before KA write)
#define OFF_VM 25600000            // VMF16 [rel][n][128]
#define OFF_KF 25600000            // alias: kF16 (dead before VM write)
#define OFF_HLO 28800000           // hLo f16 [n][128] (=VMF[1] region)
#define OFF_WKHI 48000000          // W f16x2 splits, [t][f][d], 100k spacing
#define OFF_WKLO 48100000          //   (=VMF[7] region, dead before nrg2)
#define OFF_WQHI 48200000
#define OFF_WQLO 48300000
#define OFF_QF 51200000            // qF16 — no aliasing writer after kq
#define OFF_AGGF 54400000
#define OFF_VF 54400000            // alias: vF16 (dead before attend writes agg)
#define OFF_ATTT 57600000          // attT [r][f][d] (transposed), 100k spacing
#define OFF_MSGT 57700000
#define OFF_WVT 57800000
#define OFF_WAT 57900000
#define OFF_INT 58000000           // int region, +701,872 -> 58,701,872 words
#define IO_NLIST 0                 // 51,072
#define IO_CNT_N 51072
#define IO_CUR_N 51080
#define IO_POFF_N 51088
#define IO_DCNT 51104              // 50,000
#define IO_DCUR 101104             // 50,000
#define IO_DOFF 151104             // 50,000
#define IO_DPR 201104              // 500,000 packed (src*8|rel) per CSR slot
#define IO_BLKSUM 701104           // 256 per-scan-block totals
#define IO_BLKOFF 701360           // 256 scanned block offsets; end 701,616

typedef _Float16 half8 __attribute__((ext_vector_type(8)));
typedef _Float16 half4 __attribute__((ext_vector_type(4)));
typedef float f32x4 __attribute__((ext_vector_type(4)));

__global__ void init_kernel(int* wsi) {
    int i = blockIdx.x * blockDim.x + threadIdx.x;
    if (i < NODE_LIST_LEN) wsi[IO_NLIST + i] = -1;
    if (i < 32) wsi[IO_CNT_N + i] = 0;
    if (i < 100000) wsi[IO_DCNT + i] = 0;  // dcnt + dcur contiguous
}

// weight tensors transposed to [.][f][d] f16
__global__ void convert_kernel(const float* __restrict__ att,
                               const float* __restrict__ msg,
                               const float* __restrict__ Wv,
                               const float* __restrict__ Wa,
                               _Float16* __restrict__ attT,
                               _Float16* __restrict__ msgT,
                               _Float16* __restrict__ WvT,
                               _Float16* __restrict__ WaT) {
    int i = blockIdx.x * 256 + threadIdx.x;
    if (i >= RR * DIM * DIM) return;
    int td = i >> 14, d = (i >> 7) & 127, f = i & 127;
    int tr = (td << 14) + (f << 7) + d;
    attT[tr] = (_Float16)att[i];
    msgT[tr] = (_Float16)msg[i];
    WvT[tr] = (_Float16)Wv[i];
    WaT[tr] = (_Float16)Wa[i];
}

// f16x2 split of Wk, Wq (transposed [t][f][d]): hi = f16(x), lo = f16(x-hi)
__global__ void convert2_kernel(const float* __restrict__ Wk,
                                const float* __restrict__ Wq,
                                _Float16* __restrict__ WkHiT,
                                _Float16* __restrict__ WkLoT,
                                _Float16* __restrict__ WqHiT,
                                _Float16* __restrict__ WqLoT) {
    int i = blockIdx.x * 256 + threadIdx.x;
    if (i >= TT * DIM * DIM) return;
    int td = i >> 14, d = (i >> 7) & 127, f = i & 127;
    int tr = (td << 14) + (f << 7) + d;
    float xk = Wk[i];
    _Float16 hk = (_Float16)xk;
    WkHiT[tr] = hk;
    WkLoT[tr] = (_Float16)(xk - (float)hk);  // Sterbenz: exact subtraction
    float xq = Wq[i];
    _Float16 hq = (_Float16)xq;
    WqHiT[tr] = hq;
    WqLoT[tr] = (_Float16)(xq - (float)hq);
}

// h -> hF (hi) + hLo (residual), both f16
__global__ void hconv_kernel(const float* __restrict__ h,
                             _Float16* __restrict__ hF,
                             _Float16* __restrict__ hLo) {
    int i = blockIdx.x * 256 + threadIdx.x;
    if (i < N_NODES * DIM / 4) {
        float4 v = ((const float4*)h)[i];
        half4 o, r;
        o[0] = (_Float16)v.x; o[1] = (_Float16)v.y;
        o[2] = (_Float16)v.z; o[3] = (_Float16)v.w;
        r[0] = (_Float16)(v.x - (float)o[0]);
        r[1] = (_Float16)(v.y - (float)o[1]);
        r[2] = (_Float16)(v.z - (float)o[2]);
        r[3] = (_Float16)(v.w - (float)o[3]);
        *(half4*)(hF + (size_t)i * 4) = o;
        *(half4*)(hLo + (size_t)i * 4) = r;
    }
}

__global__ void hist_kernel(const int* __restrict__ ntype,
                            const int* __restrict__ adj, int* wsi) {
    __shared__ int cn[TT];
    int tid = threadIdx.x;
    if (tid < TT) cn[tid] = 0;
    __syncthreads();
    int i = blockIdx.x * blockDim.x + tid;
    if (i < N_NODES) atomicAdd(&cn[ntype[i]], 1);
    if (i < N_EDGES) atomicAdd(&wsi[IO_DCNT + adj[N_EDGES + i]], 1);
    __syncthreads();
    if (tid < TT && cn[tid] > 0) atomicAdd(&wsi[IO_CNT_N + tid], cn[tid]);
}

__global__ void offsets_kernel(int* wsi) {
    int off = 0;
    for (int t = 0; t < TT; ++t) {
        wsi[IO_POFF_N + t] = off;
        off += ((wsi[IO_CNT_N + t] + 127) >> 7) << 7;  // pad to 128
    }
}

// 3-phase parallel exclusive scan of the 50k dst counts
__global__ __launch_bounds__(256) void scanA_kernel(int* wsi) {
    __shared__ int tmp[256];
    int tid = threadIdx.x;
    int i = blockIdx.x * 256 + tid;
    int v = (i < N_NODES) ? wsi[IO_DCNT + i] : 0;
    tmp[tid] = v;
    __syncthreads();
    for (int off = 1; off < 256; off <<= 1) {
        int t = (tid >= off) ? tmp[tid - off] : 0;
        __syncthreads();
        tmp[tid] += t;
        __syncthreads();
    }
    if (i < N_NODES) wsi[IO_DOFF + i] = tmp[tid] - v;  // block-local exclusive
    if (tid == 255) wsi[IO_BLKSUM + blockIdx.x] = tmp[255];
}

__global__ __launch_bounds__(256) void scanB_kernel(int* wsi) {
    __shared__ int tmp[256];
    int tid = threadIdx.x;
    int v = (tid < SCAN_BLOCKS) ? wsi[IO_BLKSUM + tid] : 0;
    tmp[tid] = v;
    __syncthreads();
    for (int off = 1; off < 256; off <<= 1) {
        int t = (tid >= off) ? tmp[tid - off] : 0;
        __syncthreads();
        tmp[tid] += t;
        __syncthreads();
    }
    wsi[IO_BLKOFF + tid] = tmp[tid] - v;
}

__global__ __launch_bounds__(256) void scanC_kernel(int* wsi) {
    int i = blockIdx.x * 256 + threadIdx.x;
    if (i < N_NODES) wsi[IO_DOFF + i] += wsi[IO_BLKOFF + blockIdx.x];
}

__global__ void scatter_kernel(const int* __restrict__ ntype,
                               const int* __restrict__ etype,
                               const int* __restrict__ adj, int* wsi) {
    __shared__ int cn[TT], bn[TT];
    int tid = threadIdx.x;
    if (tid < TT) cn[tid] = 0;
    __syncthreads();
    int i = blockIdx.x * blockDim.x + tid;
    int t = -1, rnk = 0;
    if (i < N_NODES) {
        t = ntype[i];
        rnk = atomicAdd(&cn[t], 1);
    }
    __syncthreads();
    if (tid < TT && cn[tid] > 0) bn[tid] = atomicAdd(&wsi[IO_CUR_N + tid], cn[tid]);
    __syncthreads();
    if (t >= 0)
        wsi[IO_NLIST + wsi[IO_POFF_N + t] + bn[t] + rnk] = i;
    if (i < N_EDGES) {
        int d = adj[N_EDGES + i];
        int pos = wsi[IO_DOFF + d] + atomicAdd(&wsi[IO_DCUR + d], 1);
        wsi[IO_DPR + pos] = (adj[i] << 3) | etype[i];  // packed src*8|rel
    }
}

// ---------------------------------------------------------------------------
// kq v7 (R24): f16x2-split MFMA with B staged in LDS. acc = hHi@WHi +
// hHi@WLo + hLo@WHi, f32 accumulate (~1e-6 rel error, R23-verified).
// B staged once/block cooperatively; [128][136] rows (272B stride) give
// even 8-slot distribution for ds_read_b128. blockIdx.y = w (k/q).
// ---------------------------------------------------------------------------
__global__ __launch_bounds__(256, 2) void kq_mfma_kernel(
    const _Float16* __restrict__ hHi, const _Float16* __restrict__ hLo,
    const int* __restrict__ ntype,
    const _Float16* __restrict__ WkHiT, const _Float16* __restrict__ WkLoT,
    const _Float16* __restrict__ WqHiT, const _Float16* __restrict__ WqLoT,
    const int* __restrict__ nlist, _Float16* __restrict__ kout,
    _Float16* __restrict__ qout) {
    __shared__ _Float16 bHiS[128][136];
    __shared__ _Float16 bLoS[128][136];
    __shared__ int nid[128];
    int tid = threadIdx.x;
    if (tid < 128) nid[tid] = nlist[blockIdx.x * 128 + tid];
    __syncthreads();
    if (nid[0] < 0) return;
    int t = ntype[nid[0]];
    int w = blockIdx.y;
    const _Float16* BHi = (w ? WqHiT : WkHiT) + (t << 14);
    const _Float16* BLo = (w ? WqLoT : WkLoT) + (t << 14);
    // cooperative stage: 2048 half8 chunks per matrix, 8 iters/thread each
    for (int i = tid; i < 2048; i += 256) {
        int row = i >> 4, col = (i & 15) * 8;
        *(half8*)&bHiS[row][col] = *(const half8*)(BHi + row * DIM + col);
        *(half8*)&bLoS[row][col] = *(const half8*)(BLo + row * DIM + col);
    }
    __syncthreads();

    int wv = tid >> 6, lane = tid & 63, l16 = lane & 15, quad = lane >> 4;
    int r0 = wv * 32;
    int nA[2];
#pragma unroll
    for (int m = 0; m < 2; ++m) nA[m] = nid[r0 + m * 16 + l16];
    _Float16* O = w ? qout : kout;
    f32x4 acc[2][8];
#pragma unroll
    for (int m = 0; m < 2; ++m)
#pragma unroll
        for (int c = 0; c < 8; ++c) acc[m][c] = (f32x4){0.f, 0.f, 0.f, 0.f};
    for (int kk = 0; kk < 4; ++kk) {
        int kb = kk * 32 + quad * 8;
        half8 aHi[2], aLo[2];
#pragma unroll
        for (int m = 0; m < 2; ++m) {
            aHi[m] = (nA[m] >= 0)
                         ? *(const half8*)(hHi + (size_t)nA[m] * DIM + kb)
                         : (half8){0, 0, 0, 0, 0, 0, 0, 0};
            aLo[m] = (nA[m] >= 0)
                         ? *(const half8*)(hLo + (size_t)nA[m] * DIM + kb)
                         : (half8){0, 0, 0, 0, 0, 0, 0, 0};
        }
#pragma unroll
        for (int c = 0; c < 8; ++c) {
            half8 bHi = *(const half8*)&bHiS[c * 16 + l16][kb];
            half8 bLo = *(const half8*)&bLoS[c * 16 + l16][kb];
#pragma unroll
            for (int m = 0; m < 2; ++m) {
                acc[m][c] = __builtin_amdgcn_mfma_f32_16x16x32_f16(
                    aHi[m], bHi, acc[m][c], 0, 0, 0);
                acc[m][c] = __builtin_amdgcn_mfma_f32_16x16x32_f16(
                    aHi[m], bLo, acc[m][c], 0, 0, 0);
                acc[m][c] = __builtin_amdgcn_mfma_f32_16x16x32_f16(
                    aLo[m], bHi, acc[m][c], 0, 0, 0);
            }
        }
    }
#pragma unroll
    for (int m = 0; m < 2; ++m)
#pragma unroll
        for (int c = 0; c < 8; ++c)
#pragma unroll
            for (int rg = 0; rg < 4; ++rg) {
                int node = nid[r0 + m * 16 + quad * 4 + rg];
                if (node >= 0)
                    O[(size_t)node * DIM + c * 16 + l16] =
                        (_Float16)acc[m][c][rg];
            }
}

// v: 128-node type-uniform chunk MFMA GEMM (value path: f16-tolerant)
__global__ __launch_bounds__(256) void vproj_kernel(
    const _Float16* __restrict__ hF, const int* __restrict__ ntype,
    const _Float16* __restrict__ WvT, const int* __restrict__ nlist,
    _Float16* __restrict__ vout) {
    __shared__ int nid[128];
    int tid = threadIdx.x;
    if (tid < 128) nid[tid] = nlist[blockIdx.x * 128 + tid];
    __syncthreads();
    if (nid[0] < 0) return;
    int t = ntype[nid[0]];
    int wv = tid >> 6, lane = tid & 63, l16 = lane & 15, quad = lane >> 4;
    int r0 = wv * 32;
    int nA[2];
#pragma unroll
    for (int m = 0; m < 2; ++m) nA[m] = nid[r0 + m * 16 + l16];
    const _Float16* B = WvT + (t << 14);
    f32x4 acc[2][8];
#pragma unroll
    for (int m = 0; m < 2; ++m)
#pragma unroll
        for (int c = 0; c < 8; ++c) acc[m][c] = (f32x4){0.f, 0.f, 0.f, 0.f};
    for (int kk = 0; kk < 4; ++kk) {
        int kb = kk * 32 + quad * 8;
        half8 a[2];
#pragma unroll
        for (int m = 0; m < 2; ++m)
            a[m] = (nA[m] >= 0)
                       ? *(const half8*)(hF + (size_t)nA[m] * DIM + kb)
                       : (half8){0, 0, 0, 0, 0, 0, 0, 0};
#pragma unroll
        for (int c = 0; c < 8; ++c) {
            half8 b = *(const half8*)(B + (c * 16 + l16) * DIM + kb);
#pragma unroll
            for (int m = 0; m < 2; ++m)
                acc[m][c] = __builtin_amdgcn_mfma_f32_16x16x32_f16(
                    a[m], b, acc[m][c], 0, 0, 0);
        }
    }
#pragma unroll
    for (int m = 0; m < 2; ++m)
#pragma unroll
        for (int c = 0; c < 8; ++c)
#pragma unroll
            for (int rg = 0; rg < 4; ++rg) {
                int node = nid[r0 + m * 16 + quad * 4 + rg];
                if (node >= 0)
                    vout[(size_t)node * DIM + c * 16 + l16] =
                        (_Float16)acc[m][c][rg];
            }
}

// ---------------------------------------------------------------------------
// nr_gemm v6 (R16-proven): one block = one rel; B register-resident; stream
// NR3_ITERS x 64-row tiles with double-buffered A prefetch.
// Pass 1: Out=KA, A=kF, B=attT, scale=pri*rsqrt. Pass 2: Out=VMF, A=vF,
// B=msgT, scale=1.
// ---------------------------------------------------------------------------
__global__ __launch_bounds__(256, 2) void nr_gemm3_kernel(
    const _Float16* __restrict__ A, const _Float16* __restrict__ B8,
    _Float16* __restrict__ Out, const float* __restrict__ pri, int isU) {
    __shared__ _Float16 stage[4][16][136];
    int bid = blockIdx.x;
    int rel = bid / NR3_CHUNKS;
    int chunk = bid - rel * NR3_CHUNKS;
    float scale = isU ? pri[rel] * RSQRT_DK : 1.0f;
    const _Float16* Bb = B8 + (rel << 14);
    int tid = threadIdx.x;
    int wv = tid >> 6, lane = tid & 63;
    int l16 = lane & 15, quad = lane >> 4;

    // B fragments once: bfrag[c][kk] covers B-row c*16+l16, k=kk*32+quad*8
    half8 bfrag[8][4];
#pragma unroll
    for (int c = 0; c < 8; ++c)
#pragma unroll
        for (int kk = 0; kk < 4; ++kk)
            bfrag[c][kk] =
                *(const half8*)(Bb + (c * 16 + l16) * DIM + kk * 32 + quad * 8);

    _Float16* Orel = Out + (size_t)rel * N_NODES * DIM;
    int base = chunk * NR3_ROWS + wv * 16;  // this wave's first tile row

    // prefetch tile 0
    half8 aNow[4], aNext[4];
    {
        int nodeA = base + l16;
#pragma unroll
        for (int kk = 0; kk < 4; ++kk)
            aNow[kk] = (nodeA < N_NODES)
                           ? *(const half8*)(A + (size_t)nodeA * DIM +
                                             kk * 32 + quad * 8)
                           : (half8){0, 0, 0, 0, 0, 0, 0, 0};
    }

    for (int it = 0; it < NR3_ITERS; ++it) {
        int row0 = base + it * 64;
        // prefetch next tile's A while this tile computes
        if (it + 1 < NR3_ITERS) {
            int nodeA = row0 + 64 + l16;
#pragma unroll
            for (int kk = 0; kk < 4; ++kk)
                aNext[kk] = (nodeA < N_NODES)
                                ? *(const half8*)(A + (size_t)nodeA * DIM +
                                                  kk * 32 + quad * 8)
                                : (half8){0, 0, 0, 0, 0, 0, 0, 0};
        }
        f32x4 acc[8];
#pragma unroll
        for (int c = 0; c < 8; ++c) acc[c] = (f32x4){0.f, 0.f, 0.f, 0.f};
#pragma unroll
        for (int kk = 0; kk < 4; ++kk)
#pragma unroll
            for (int c = 0; c < 8; ++c)
                acc[c] = __builtin_amdgcn_mfma_f32_16x16x32_f16(
                    bfrag[c][kk], aNow[kk], acc[c], 0, 0, 0);
        // stage transposed acc into wave-private LDS: row = local node l16,
        // feature = c*16 + quad*4 + rg
#pragma unroll
        for (int c = 0; c < 8; ++c) {
            half4 o;
#pragma unroll
            for (int rg = 0; rg < 4; ++rg)
                o[rg] = (_Float16)(acc[c][rg] * scale);
            *(half4*)&stage[wv][l16][c * 16 + quad * 4] = o;
        }
        // read back row-wise: 4 x (4 rows x 256B) = 1KiB contiguous stores
        _Float16* Op = Orel + (size_t)row0 * DIM;
#pragma unroll
        for (int s = 0; s < 4; ++s) {
            int row = s * 4 + quad;
            if (row0 + row < N_NODES) {
                half8 v = *(const half8*)&stage[wv][row][l16 * 8];
                *(half8*)(Op + (size_t)row * DIM + l16 * 8) = v;
            }
        }
#pragma unroll
        for (int kk = 0; kk < 4; ++kk) aNow[kk] = aNext[kk];
    }
}

// ---------------------------------------------------------------------------
// attend v4 (R22): score = kA[rel][src] . q[dst]. One gather per edge in
// phase 1; q[dst] register-resident; online per-rel softmax (R21); no LDS.
// ---------------------------------------------------------------------------
__global__ __launch_bounds__(256) void attend_kernel(
    const _Float16* __restrict__ KA, const _Float16* __restrict__ qF,
    const _Float16* __restrict__ VMF, const int* __restrict__ dpr,
    const int* __restrict__ doff, const int* __restrict__ dcnt,
    _Float16* __restrict__ aggF) {
    int wv = threadIdx.x >> 6, lane = threadIdx.x & 63;
    int dst = blockIdx.x * 4 + wv;
    if (dst >= N_NODES) return;
    int l16 = lane & 15, g = lane >> 4, l8 = lane & 7;
    int beg = doff[dst], cnt = dcnt[dst];

    // q[dst] fragment: 8 halves per lane, register-resident for the kernel
    half8 qv = *(const half8*)(qF + (size_t)dst * DIM + l16 * 8);

    float m_own = -3e38f, sum_own = 0.f;
    float s0 = 0.f, s1 = 0.f, s2 = 0.f;
    int p0 = 0, p1 = 0, p2 = 0;

    // phase 1: scores; park (s, pr); ONLINE per-rel (max, sum) on owning lane
    for (int j0 = 0; j0 < cnt; j0 += 4) {
        int j = j0 + g;
        bool valid = j < cnt;
        int pr = valid ? dpr[beg + j] : 0;
        int src = pr >> 3, rel = pr & 7;
        half8 kv = *(const half8*)(KA + ((size_t)rel * N_NODES + src) * DIM +
                                   l16 * 8);
        float sa = 0.f, sb = 0.f;
#pragma unroll
        for (int i = 0; i < 4; ++i) sa += (float)kv[i] * (float)qv[i];
#pragma unroll
        for (int i = 4; i < 8; ++i) sb += (float)kv[i] * (float)qv[i];
        float s = sa + sb;
        s += __shfl_xor(s, 1, 16);
        s += __shfl_xor(s, 2, 16);
        s += __shfl_xor(s, 4, 16);
        s += __shfl_xor(s, 8, 16);
        if (!valid) s = -3e38f;
        int slot = j0 >> 6;            // wave-uniform
        int idx = (j0 >> 2) & 15;      // wave-uniform
        if (l16 == idx) {
            if (slot == 0) { s0 = s; p0 = pr; }
            else if (slot == 1) { s1 = s; p1 = pr; }
            else if (slot == 2) { s2 = s; p2 = pr; }
        }
        if (valid && l8 == rel) {
            if (s > m_own) {
                sum_own *= __expf(m_own - s);  // 0 * exp(-huge) = 0 first time
                m_own = s;
            }
            sum_own += __expf(s - m_own);
        }
    }
    // joint merge of (m, sum) across the 4 groups (exp-rescale combine)
    {
        float m2 = __shfl_xor(m_own, 16, 64);
        float t2 = __shfl_xor(sum_own, 16, 64);
        float mn = fmaxf(m_own, m2);
        sum_own = sum_own * __expf(m_own - mn) + t2 * __expf(m2 - mn);
        m_own = mn;
        m2 = __shfl_xor(m_own, 32, 64);
        t2 = __shfl_xor(sum_own, 32, 64);
        mn = fmaxf(m_own, m2);
        sum_own = sum_own * __expf(m_own - mn) + t2 * __expf(m2 - mn);
        m_own = mn;
    }
    float inv_own = (sum_own > 0.f) ? 1.f / sum_own : 0.f;

    // phase 2: alpha = exp(s - m[rel]) * inv[rel]; acc += alpha * VM[rel][src]
    float acc[8] = {0.f, 0.f, 0.f, 0.f, 0.f, 0.f, 0.f, 0.f};
    for (int j0 = 0; j0 < cnt; j0 += 4) {
        int j = j0 + g;
        bool valid = j < cnt;
        int slot = j0 >> 6;
        int idx = (j0 >> 2) & 15;
        float s;
        int pr;
        if (slot < 3) {
            float sv = (slot == 0) ? s0 : (slot == 1) ? s1 : s2;
            int pv = (slot == 0) ? p0 : (slot == 1) ? p1 : p2;
            s = __shfl(sv, idx, 16);
            pr = __shfl(pv, idx, 16);
        } else {  // overflow fallback: recompute (cnt>192 ~ never at deg~10)
            pr = valid ? dpr[beg + j] : 0;
            int src = pr >> 3, rel = pr & 7;
            half8 kv = *(const half8*)(KA +
                                       ((size_t)rel * N_NODES + src) * DIM +
                                       l16 * 8);
            float sa = 0.f, sb = 0.f;
#pragma unroll
            for (int i = 0; i < 4; ++i) sa += (float)kv[i] * (float)qv[i];
#pragma unroll
            for (int i = 4; i < 8; ++i) sb += (float)kv[i] * (float)qv[i];
            s = sa + sb;
            s += __shfl_xor(s, 1, 16);
            s += __shfl_xor(s, 2, 16);
            s += __shfl_xor(s, 4, 16);
            s += __shfl_xor(s, 8, 16);
        }
        int rel = pr & 7, src = pr >> 3;
        float mr = __shfl(m_own, rel, 8);
        float iv = __shfl(inv_own, rel, 8);
        float alpha = valid ? __expf(s - mr) * iv : 0.f;
        half8 v = *(const half8*)(VMF + ((size_t)rel * N_NODES + src) * DIM +
                                  l16 * 8);
#pragma unroll
        for (int i = 0; i < 8; ++i) acc[i] += alpha * (float)v[i];
    }
    // merge acc across the 4 groups (each covers the full 128 dims)
#pragma unroll
    for (int i = 0; i < 8; ++i) {
        acc[i] += __shfl_xor(acc[i], 16, 64);
        acc[i] += __shfl_xor(acc[i], 32, 64);
    }
    if (g == 0) {
        half8 o;
#pragma unroll
        for (int i = 0; i < 8; ++i) o[i] = (_Float16)acc[i];
        *(half8*)(aggF + (size_t)dst * DIM + l16 * 8) = o;
    }
}

// out: 128-node type-uniform chunk MFMA GEMM, fp32 stores with sigmoid gate
__global__ __launch_bounds__(256) void out_kernel(
    const _Float16* __restrict__ aggF, const int* __restrict__ ntype,
    const _Float16* __restrict__ WaT, const float* __restrict__ skip,
    const int* __restrict__ nlist, float* __restrict__ out) {
    __shared__ int nid[128];
    int tid = threadIdx.x;
    if (tid < 128) nid[tid] = nlist[blockIdx.x * 128 + tid];
    __syncthreads();
    if (nid[0] < 0) return;
    int t = ntype[nid[0]];
    float sig = 1.f / (1.f + __expf(-skip[t]));
    int wv = tid >> 6, lane = tid & 63, l16 = lane & 15, quad = lane >> 4;
    int r0 = wv * 32;
    int nA[2];
#pragma unroll
    for (int m = 0; m < 2; ++m) nA[m] = nid[r0 + m * 16 + l16];
    const _Float16* B = WaT + (t << 14);
    f32x4 acc[2][8];
#pragma unroll
    for (int m = 0; m < 2; ++m)
#pragma unroll
        for (int c = 0; c < 8; ++c) acc[m][c] = (f32x4){0.f, 0.f, 0.f, 0.f};
    for (int kk = 0; kk < 4; ++kk) {
        int kb = kk * 32 + quad * 8;
        half8 a[2];
#pragma unroll
        for (int m = 0; m < 2; ++m)
            a[m] = (nA[m] >= 0)
                       ? *(const half8*)(aggF + (size_t)nA[m] * DIM + kb)
                       : (half8){0, 0, 0, 0, 0, 0, 0, 0};
#pragma unroll
        for (int c = 0; c < 8; ++c) {
            half8 b = *(const half8*)(B + (c * 16 + l16) * DIM + kb);
#pragma unroll
            for (int m = 0; m < 2; ++m)
                acc[m][c] = __builtin_amdgcn_mfma_f32_16x16x32_f16(
                    a[m], b, acc[m][c], 0, 0, 0);
        }
    }
#pragma unroll
    for (int m = 0; m < 2; ++m)
#pragma unroll
        for (int c = 0; c < 8; ++c)
#pragma unroll
            for (int rg = 0; rg < 4; ++rg) {
                int node = nid[r0 + m * 16 + quad * 4 + rg];
                if (node >= 0)
                    out[(size_t)node * DIM + c * 16 + l16] =
                        acc[m][c][rg] * sig;
            }
}

extern "C" void kernel_launch(void* const* d_in, const int* in_sizes, int n_in,
                              void* d_out, int out_size, void* d_ws,
                              size_t ws_size, hipStream_t stream) {
    const float* h = (const float*)d_in[0];
    const int* adj = (const int*)d_in[1];
    const int* etype = (const int*)d_in[2];
    const int* ntype = (const int*)d_in[3];
    const float* Wk = (const float*)d_in[6];
    const float* Wq = (const float*)d_in[7];
    const float* Wv = (const float*)d_in[8];
    const float* Wa = (const float*)d_in[9];
    const float* pri = (const float*)d_in[10];
    const float* att = (const float*)d_in[11];
    const float* msg = (const float*)d_in[12];
    const float* skip = (const float*)d_in[13];
    float* out = (float*)d_out;

    int* wsi = (int*)d_ws + OFF_INT;
    _Float16* wsh = (_Float16*)d_ws;
    _Float16* KA = wsh + (size_t)OFF_KA * 2;
    _Float16* hF = wsh + (size_t)OFF_HF * 2;
    _Float16* hLo = wsh + (size_t)OFF_HLO * 2;
    _Float16* VMF = wsh + (size_t)OFF_VM * 2;
    _Float16* kF = wsh + (size_t)OFF_KF * 2;
    _Float16* qF = wsh + (size_t)OFF_QF * 2;
    _Float16* aggF = wsh + (size_t)OFF_AGGF * 2;
    _Float16* vF = wsh + (size_t)OFF_VF * 2;
    _Float16* attT = wsh + (size_t)OFF_ATTT * 2;
    _Float16* msgT = wsh + (size_t)OFF_MSGT * 2;
    _Float16* WvT = wsh + (size_t)OFF_WVT * 2;
    _Float16* WaT = wsh + (size_t)OFF_WAT * 2;
    _Float16* WkHiT = wsh + (size_t)OFF_WKHI * 2;
    _Float16* WkLoT = wsh + (size_t)OFF_WKLO * 2;
    _Float16* WqHiT = wsh + (size_t)OFF_WQHI * 2;
    _Float16* WqLoT = wsh + (size_t)OFF_WQLO * 2;

    init_kernel<<<(100000 + 255) / 256, 256, 0, stream>>>(wsi);
    convert_kernel<<<(RR * DIM * DIM + 255) / 256, 256, 0, stream>>>(
        att, msg, Wv, Wa, attT, msgT, WvT, WaT);
    convert2_kernel<<<(TT * DIM * DIM + 255) / 256, 256, 0, stream>>>(
        Wk, Wq, WkHiT, WkLoT, WqHiT, WqLoT);
    hconv_kernel<<<(N_NODES * DIM / 4 + 255) / 256, 256, 0, stream>>>(h, hF,
                                                                      hLo);
    hist_kernel<<<GRID_E, 256, 0, stream>>>(ntype, adj, wsi);
    offsets_kernel<<<1, 1, 0, stream>>>(wsi);
    scanA_kernel<<<SCAN_BLOCKS, 256, 0, stream>>>(wsi);
    scanB_kernel<<<1, 256, 0, stream>>>(wsi);
    scanC_kernel<<<SCAN_BLOCKS, 256, 0, stream>>>(wsi);
    scatter_kernel<<<GRID_E, 256, 0, stream>>>(ntype, etype, adj, wsi);
    {
        dim3 g(CHUNK_GRID, 2);  // x: 128-node chunks, y: w (k=0, q=1)
        kq_mfma_kernel<<<g, 256, 0, stream>>>(hF, hLo, ntype, WkHiT, WkLoT,
                                              WqHiT, WqLoT, wsi + IO_NLIST,
                                              kF, qF);
    }
    vproj_kernel<<<CHUNK_GRID, 256, 0, stream>>>(hF, ntype, WvT,
                                                 wsi + IO_NLIST, vF);
    // pass 1: KA = pri*rsqrt * (kF @ attT^T); writes over hF region (dead).
    // pass 2: VMF = vF @ msgT^T; writes over kF/hLo/Wsplit regions (dead).
    nr_gemm3_kernel<<<RR * NR3_CHUNKS, 256, 0, stream>>>(kF, attT, KA, pri, 1);
    nr_gemm3_kernel<<<RR * NR3_CHUNKS, 256, 0, stream>>>(vF, msgT, VMF, pri, 0);
    attend_kernel<<<(N_NODES + 3) / 4, 256, 0, stream>>>(
        KA, qF, VMF, wsi + IO_DPR, wsi + IO_DOFF, wsi + IO_DCNT, aggF);
    out_kernel<<<CHUNK_GRID, 256, 0, stream>>>(aggF, ntype, WaT, skip,
                                               wsi + IO_NLIST, out);
}

// Round 14
// 357.873 us; speedup vs baseline: 1.0706x; 1.0030x over previous
//
#include <hip/hip_runtime.h>
#include <math.h>

// ---------------------------------------------------------------------------
// HGT layer slice. R25: attend v5 — v_dot2_f32_f16 dots + pre-packed row idx.
// R24 post-mortem: LDS-staged B confirmed (total 383->359; kq out of top-5).
// attend leads at 51us: VALU 60% (~31us busy) > HBM term (132MB ~ 21us) —
// compute-overhead-bound per edge. Fixes: (1) score dot via
// __builtin_amdgcn_fdot2 (4 dot2 + 1 add vs ~16 cvt/fma; f16-in f32-acc,
// ~1e-7 perturbation class already accepted R21/R22); (2) dpr re-packed by
// scatter as ((rel*N+src)<<3)|rel — KA and VM share row rel*N+src, so the
// per-edge 64-bit addr mul collapses to a shift in both phases.
//
// kq v7 LDS-staged f16x2 MFMA (R24), attend v4 factorization (R22), online
// softmax (R21), nr_gemm v6 (R16), parallel scan (R10), [rel][node] (R12).
// ---------------------------------------------------------------------------

#define N_NODES 50000
#define N_EDGES 500000
#define DIM 128
#define TT 8
#define RR 8
#define RSQRT_DK 0.08838834764831845f

#define CHUNK_GRID 399               // 399*128 = 51072 >= 50000 + 8*127
#define NODE_LIST_LEN (CHUNK_GRID * 128)
#define GRID_E ((N_EDGES + 255) / 256)   // 1954, also covers N
#define SCAN_BLOCKS ((N_NODES + 255) / 256)   // 196

// nr_gemm v6 geometry: 112 chunks x 448 rows (7 iters x 64) = 50176 >= 50000
#define NR3_CHUNKS 112
#define NR3_ROWS 448
#define NR3_ITERS 7

// word offsets (4B units); _Float16 index = 2*word
// Lifetime audit (stream order: kq_mfma -> vproj -> nrg1(KA) -> nrg2(VM) ->
// attend -> out):
//   KA  @ 0..25.6M    written by nrg1; hF alias dead after vproj
//   VMF @ 25.6..51.2M written by nrg2; kF/hLo/Wsplit aliases dead by then
//   kF  @ 25.6M       written by kq_mfma, read by nrg1, clobbered by nrg2 OK
//   hLo @ 28.8M       (=VMF[1]) written by hconv, read by kq_mfma, dead
//   Wsplit@48.0-48.3M (=VMF[7]) written by convert2, read by kq_mfma, dead
//   qF  @ 51.2M       written by kq_mfma, read by attend; no aliasing writer
//   aggF@ 54.4M       written by attend, read by out; vF alias dead by then
#define OFF_KA 0                   // kA f16 [rel][n][128]
#define OFF_HF 0                   // alias: hF16 = hHi (dead before KA write)
#define OFF_VM 25600000            // VMF16 [rel][n][128]
#define OFF_KF 25600000            // alias: kF16 (dead before VM write)
#define OFF_HLO 28800000           // hLo f16 [n][128] (=VMF[1] region)
#define OFF_WKHI 48000000          // W f16x2 splits, [t][f][d], 100k spacing
#define OFF_WKLO 48100000          //   (=VMF[7] region, dead before nrg2)
#define OFF_WQHI 48200000
#define OFF_WQLO 48300000
#define OFF_QF 51200000            // qF16 — no aliasing writer after kq
#define OFF_AGGF 54400000
#define OFF_VF 54400000            // alias: vF16 (dead before attend writes agg)
#define OFF_ATTT 57600000          // attT [r][f][d] (transposed), 100k spacing
#define OFF_MSGT 57700000
#define OFF_WVT 57800000
#define OFF_WAT 57900000
#define OFF_INT 58000000           // int region, +701,872 -> 58,701,872 words
#define IO_NLIST 0                 // 51,072
#define IO_CNT_N 51072
#define IO_CUR_N 51080
#define IO_POFF_N 51088
#define IO_DCNT 51104              // 50,000
#define IO_DCUR 101104             // 50,000
#define IO_DOFF 151104             // 50,000
#define IO_DPR 201104              // 500,000 packed ((rel*N+src)*8|rel)
#define IO_BLKSUM 701104           // 256 per-scan-block totals
#define IO_BLKOFF 701360           // 256 scanned block offsets; end 701,616

typedef _Float16 half8 __attribute__((ext_vector_type(8)));
typedef _Float16 half4 __attribute__((ext_vector_type(4)));
typedef _Float16 half2 __attribute__((ext_vector_type(2)));
typedef float f32x4 __attribute__((ext_vector_type(4)));

__global__ void init_kernel(int* wsi) {
    int i = blockIdx.x * blockDim.x + threadIdx.x;
    if (i < NODE_LIST_LEN) wsi[IO_NLIST + i] = -1;
    if (i < 32) wsi[IO_CNT_N + i] = 0;
    if (i < 100000) wsi[IO_DCNT + i] = 0;  // dcnt + dcur contiguous
}

// weight tensors transposed to [.][f][d] f16
__global__ void convert_kernel(const float* __restrict__ att,
                               const float* __restrict__ msg,
                               const float* __restrict__ Wv,
                               const float* __restrict__ Wa,
                               _Float16* __restrict__ attT,
                               _Float16* __restrict__ msgT,
                               _Float16* __restrict__ WvT,
                               _Float16* __restrict__ WaT) {
    int i = blockIdx.x * 256 + threadIdx.x;
    if (i >= RR * DIM * DIM) return;
    int td = i >> 14, d = (i >> 7) & 127, f = i & 127;
    int tr = (td << 14) + (f << 7) + d;
    attT[tr] = (_Float16)att[i];
    msgT[tr] = (_Float16)msg[i];
    WvT[tr] = (_Float16)Wv[i];
    WaT[tr] = (_Float16)Wa[i];
}

// f16x2 split of Wk, Wq (transposed [t][f][d]): hi = f16(x), lo = f16(x-hi)
__global__ void convert2_kernel(const float* __restrict__ Wk,
                                const float* __restrict__ Wq,
                                _Float16* __restrict__ WkHiT,
                                _Float16* __restrict__ WkLoT,
                                _Float16* __restrict__ WqHiT,
                                _Float16* __restrict__ WqLoT) {
    int i = blockIdx.x * 256 + threadIdx.x;
    if (i >= TT * DIM * DIM) return;
    int td = i >> 14, d = (i >> 7) & 127, f = i & 127;
    int tr = (td << 14) + (f << 7) + d;
    float xk = Wk[i];
    _Float16 hk = (_Float16)xk;
    WkHiT[tr] = hk;
    WkLoT[tr] = (_Float16)(xk - (float)hk);  // Sterbenz: exact subtraction
    float xq = Wq[i];
    _Float16 hq = (_Float16)xq;
    WqHiT[tr] = hq;
    WqLoT[tr] = (_Float16)(xq - (float)hq);
}

// h -> hF (hi) + hLo (residual), both f16
__global__ void hconv_kernel(const float* __restrict__ h,
                             _Float16* __restrict__ hF,
                             _Float16* __restrict__ hLo) {
    int i = blockIdx.x * 256 + threadIdx.x;
    if (i < N_NODES * DIM / 4) {
        float4 v = ((const float4*)h)[i];
        half4 o, r;
        o[0] = (_Float16)v.x; o[1] = (_Float16)v.y;
        o[2] = (_Float16)v.z; o[3] = (_Float16)v.w;
        r[0] = (_Float16)(v.x - (float)o[0]);
        r[1] = (_Float16)(v.y - (float)o[1]);
        r[2] = (_Float16)(v.z - (float)o[2]);
        r[3] = (_Float16)(v.w - (float)o[3]);
        *(half4*)(hF + (size_t)i * 4) = o;
        *(half4*)(hLo + (size_t)i * 4) = r;
    }
}

__global__ void hist_kernel(const int* __restrict__ ntype,
                            const int* __restrict__ adj, int* wsi) {
    __shared__ int cn[TT];
    int tid = threadIdx.x;
    if (tid < TT) cn[tid] = 0;
    __syncthreads();
    int i = blockIdx.x * blockDim.x + tid;
    if (i < N_NODES) atomicAdd(&cn[ntype[i]], 1);
    if (i < N_EDGES) atomicAdd(&wsi[IO_DCNT + adj[N_EDGES + i]], 1);
    __syncthreads();
    if (tid < TT && cn[tid] > 0) atomicAdd(&wsi[IO_CNT_N + tid], cn[tid]);
}

__global__ void offsets_kernel(int* wsi) {
    int off = 0;
    for (int t = 0; t < TT; ++t) {
        wsi[IO_POFF_N + t] = off;
        off += ((wsi[IO_CNT_N + t] + 127) >> 7) << 7;  // pad to 128
    }
}

// 3-phase parallel exclusive scan of the 50k dst counts
__global__ __launch_bounds__(256) void scanA_kernel(int* wsi) {
    __shared__ int tmp[256];
    int tid = threadIdx.x;
    int i = blockIdx.x * 256 + tid;
    int v = (i < N_NODES) ? wsi[IO_DCNT + i] : 0;
    tmp[tid] = v;
    __syncthreads();
    for (int off = 1; off < 256; off <<= 1) {
        int t = (tid >= off) ? tmp[tid - off] : 0;
        __syncthreads();
        tmp[tid] += t;
        __syncthreads();
    }
    if (i < N_NODES) wsi[IO_DOFF + i] = tmp[tid] - v;  // block-local exclusive
    if (tid == 255) wsi[IO_BLKSUM + blockIdx.x] = tmp[255];
}

__global__ __launch_bounds__(256) void scanB_kernel(int* wsi) {
    __shared__ int tmp[256];
    int tid = threadIdx.x;
    int v = (tid < SCAN_BLOCKS) ? wsi[IO_BLKSUM + tid] : 0;
    tmp[tid] = v;
    __syncthreads();
    for (int off = 1; off < 256; off <<= 1) {
        int t = (tid >= off) ? tmp[tid - off] : 0;
        __syncthreads();
        tmp[tid] += t;
        __syncthreads();
    }
    wsi[IO_BLKOFF + tid] = tmp[tid] - v;
}

__global__ __launch_bounds__(256) void scanC_kernel(int* wsi) {
    int i = blockIdx.x * 256 + threadIdx.x;
    if (i < N_NODES) wsi[IO_DOFF + i] += wsi[IO_BLKOFF + blockIdx.x];
}

// dpr pack: ((rel*N_NODES+src) << 3) | rel  — row index for KA/VM gathers
// plus rel in the low bits; fits 22+3 bits.
__global__ void scatter_kernel(const int* __restrict__ ntype,
                               const int* __restrict__ etype,
                               const int* __restrict__ adj, int* wsi) {
    __shared__ int cn[TT], bn[TT];
    int tid = threadIdx.x;
    if (tid < TT) cn[tid] = 0;
    __syncthreads();
    int i = blockIdx.x * blockDim.x + tid;
    int t = -1, rnk = 0;
    if (i < N_NODES) {
        t = ntype[i];
        rnk = atomicAdd(&cn[t], 1);
    }
    __syncthreads();
    if (tid < TT && cn[tid] > 0) bn[tid] = atomicAdd(&wsi[IO_CUR_N + tid], cn[tid]);
    __syncthreads();
    if (t >= 0)
        wsi[IO_NLIST + wsi[IO_POFF_N + t] + bn[t] + rnk] = i;
    if (i < N_EDGES) {
        int d = adj[N_EDGES + i];
        int pos = wsi[IO_DOFF + d] + atomicAdd(&wsi[IO_DCUR + d], 1);
        int rel = etype[i];
        wsi[IO_DPR + pos] = ((rel * N_NODES + adj[i]) << 3) | rel;
    }
}

// ---------------------------------------------------------------------------
// kq v7 (R24-proven): f16x2-split MFMA with B staged in LDS.
// ---------------------------------------------------------------------------
__global__ __launch_bounds__(256, 2) void kq_mfma_kernel(
    const _Float16* __restrict__ hHi, const _Float16* __restrict__ hLo,
    const int* __restrict__ ntype,
    const _Float16* __restrict__ WkHiT, const _Float16* __restrict__ WkLoT,
    const _Float16* __restrict__ WqHiT, const _Float16* __restrict__ WqLoT,
    const int* __restrict__ nlist, _Float16* __restrict__ kout,
    _Float16* __restrict__ qout) {
    __shared__ _Float16 bHiS[128][136];
    __shared__ _Float16 bLoS[128][136];
    __shared__ int nid[128];
    int tid = threadIdx.x;
    if (tid < 128) nid[tid] = nlist[blockIdx.x * 128 + tid];
    __syncthreads();
    if (nid[0] < 0) return;
    int t = ntype[nid[0]];
    int w = blockIdx.y;
    const _Float16* BHi = (w ? WqHiT : WkHiT) + (t << 14);
    const _Float16* BLo = (w ? WqLoT : WkLoT) + (t << 14);
    // cooperative stage: 2048 half8 chunks per matrix, 8 iters/thread each
    for (int i = tid; i < 2048; i += 256) {
        int row = i >> 4, col = (i & 15) * 8;
        *(half8*)&bHiS[row][col] = *(const half8*)(BHi + row * DIM + col);
        *(half8*)&bLoS[row][col] = *(const half8*)(BLo + row * DIM + col);
    }
    __syncthreads();

    int wv = tid >> 6, lane = tid & 63, l16 = lane & 15, quad = lane >> 4;
    int r0 = wv * 32;
    int nA[2];
#pragma unroll
    for (int m = 0; m < 2; ++m) nA[m] = nid[r0 + m * 16 + l16];
    _Float16* O = w ? qout : kout;
    f32x4 acc[2][8];
#pragma unroll
    for (int m = 0; m < 2; ++m)
#pragma unroll
        for (int c = 0; c < 8; ++c) acc[m][c] = (f32x4){0.f, 0.f, 0.f, 0.f};
    for (int kk = 0; kk < 4; ++kk) {
        int kb = kk * 32 + quad * 8;
        half8 aHi[2], aLo[2];
#pragma unroll
        for (int m = 0; m < 2; ++m) {
            aHi[m] = (nA[m] >= 0)
                         ? *(const half8*)(hHi + (size_t)nA[m] * DIM + kb)
                         : (half8){0, 0, 0, 0, 0, 0, 0, 0};
            aLo[m] = (nA[m] >= 0)
                         ? *(const half8*)(hLo + (size_t)nA[m] * DIM + kb)
                         : (half8){0, 0, 0, 0, 0, 0, 0, 0};
        }
#pragma unroll
        for (int c = 0; c < 8; ++c) {
            half8 bHi = *(const half8*)&bHiS[c * 16 + l16][kb];
            half8 bLo = *(const half8*)&bLoS[c * 16 + l16][kb];
#pragma unroll
            for (int m = 0; m < 2; ++m) {
                acc[m][c] = __builtin_amdgcn_mfma_f32_16x16x32_f16(
                    aHi[m], bHi, acc[m][c], 0, 0, 0);
                acc[m][c] = __builtin_amdgcn_mfma_f32_16x16x32_f16(
                    aHi[m], bLo, acc[m][c], 0, 0, 0);
                acc[m][c] = __builtin_amdgcn_mfma_f32_16x16x32_f16(
                    aLo[m], bHi, acc[m][c], 0, 0, 0);
            }
        }
    }
#pragma unroll
    for (int m = 0; m < 2; ++m)
#pragma unroll
        for (int c = 0; c < 8; ++c)
#pragma unroll
            for (int rg = 0; rg < 4; ++rg) {
                int node = nid[r0 + m * 16 + quad * 4 + rg];
                if (node >= 0)
                    O[(size_t)node * DIM + c * 16 + l16] =
                        (_Float16)acc[m][c][rg];
            }
}

// v: 128-node type-uniform chunk MFMA GEMM (value path: f16-tolerant)
__global__ __launch_bounds__(256) void vproj_kernel(
    const _Float16* __restrict__ hF, const int* __restrict__ ntype,
    const _Float16* __restrict__ WvT, const int* __restrict__ nlist,
    _Float16* __restrict__ vout) {
    __shared__ int nid[128];
    int tid = threadIdx.x;
    if (tid < 128) nid[tid] = nlist[blockIdx.x * 128 + tid];
    __syncthreads();
    if (nid[0] < 0) return;
    int t = ntype[nid[0]];
    int wv = tid >> 6, lane = tid & 63, l16 = lane & 15, quad = lane >> 4;
    int r0 = wv * 32;
    int nA[2];
#pragma unroll
    for (int m = 0; m < 2; ++m) nA[m] = nid[r0 + m * 16 + l16];
    const _Float16* B = WvT + (t << 14);
    f32x4 acc[2][8];
#pragma unroll
    for (int m = 0; m < 2; ++m)
#pragma unroll
        for (int c = 0; c < 8; ++c) acc[m][c] = (f32x4){0.f, 0.f, 0.f, 0.f};
    for (int kk = 0; kk < 4; ++kk) {
        int kb = kk * 32 + quad * 8;
        half8 a[2];
#pragma unroll
        for (int m = 0; m < 2; ++m)
            a[m] = (nA[m] >= 0)
                       ? *(const half8*)(hF + (size_t)nA[m] * DIM + kb)
                       : (half8){0, 0, 0, 0, 0, 0, 0, 0};
#pragma unroll
        for (int c = 0; c < 8; ++c) {
            half8 b = *(const half8*)(B + (c * 16 + l16) * DIM + kb);
#pragma unroll
            for (int m = 0; m < 2; ++m)
                acc[m][c] = __builtin_amdgcn_mfma_f32_16x16x32_f16(
                    a[m], b, acc[m][c], 0, 0, 0);
        }
    }
#pragma unroll
    for (int m = 0; m < 2; ++m)
#pragma unroll
        for (int c = 0; c < 8; ++c)
#pragma unroll
            for (int rg = 0; rg < 4; ++rg) {
                int node = nid[r0 + m * 16 + quad * 4 + rg];
                if (node >= 0)
                    vout[(size_t)node * DIM + c * 16 + l16] =
                        (_Float16)acc[m][c][rg];
            }
}

// ---------------------------------------------------------------------------
// nr_gemm v6 (R16-proven): one block = one rel; B register-resident; stream
// NR3_ITERS x 64-row tiles with double-buffered A prefetch.
// ---------------------------------------------------------------------------
__global__ __launch_bounds__(256, 2) void nr_gemm3_kernel(
    const _Float16* __restrict__ A, const _Float16* __restrict__ B8,
    _Float16* __restrict__ Out, const float* __restrict__ pri, int isU) {
    __shared__ _Float16 stage[4][16][136];
    int bid = blockIdx.x;
    int rel = bid / NR3_CHUNKS;
    int chunk = bid - rel * NR3_CHUNKS;
    float scale = isU ? pri[rel] * RSQRT_DK : 1.0f;
    const _Float16* Bb = B8 + (rel << 14);
    int tid = threadIdx.x;
    int wv = tid >> 6, lane = tid & 63;
    int l16 = lane & 15, quad = lane >> 4;

    half8 bfrag[8][4];
#pragma unroll
    for (int c = 0; c < 8; ++c)
#pragma unroll
        for (int kk = 0; kk < 4; ++kk)
            bfrag[c][kk] =
                *(const half8*)(Bb + (c * 16 + l16) * DIM + kk * 32 + quad * 8);

    _Float16* Orel = Out + (size_t)rel * N_NODES * DIM;
    int base = chunk * NR3_ROWS + wv * 16;  // this wave's first tile row

    half8 aNow[4], aNext[4];
    {
        int nodeA = base + l16;
#pragma unroll
        for (int kk = 0; kk < 4; ++kk)
            aNow[kk] = (nodeA < N_NODES)
                           ? *(const half8*)(A + (size_t)nodeA * DIM +
                                             kk * 32 + quad * 8)
                           : (half8){0, 0, 0, 0, 0, 0, 0, 0};
    }

    for (int it = 0; it < NR3_ITERS; ++it) {
        int row0 = base + it * 64;
        if (it + 1 < NR3_ITERS) {
            int nodeA = row0 + 64 + l16;
#pragma unroll
            for (int kk = 0; kk < 4; ++kk)
                aNext[kk] = (nodeA < N_NODES)
                                ? *(const half8*)(A + (size_t)nodeA * DIM +
                                                  kk * 32 + quad * 8)
                                : (half8){0, 0, 0, 0, 0, 0, 0, 0};
        }
        f32x4 acc[8];
#pragma unroll
        for (int c = 0; c < 8; ++c) acc[c] = (f32x4){0.f, 0.f, 0.f, 0.f};
#pragma unroll
        for (int kk = 0; kk < 4; ++kk)
#pragma unroll
            for (int c = 0; c < 8; ++c)
                acc[c] = __builtin_amdgcn_mfma_f32_16x16x32_f16(
                    bfrag[c][kk], aNow[kk], acc[c], 0, 0, 0);
#pragma unroll
        for (int c = 0; c < 8; ++c) {
            half4 o;
#pragma unroll
            for (int rg = 0; rg < 4; ++rg)
                o[rg] = (_Float16)(acc[c][rg] * scale);
            *(half4*)&stage[wv][l16][c * 16 + quad * 4] = o;
        }
        _Float16* Op = Orel + (size_t)row0 * DIM;
#pragma unroll
        for (int s = 0; s < 4; ++s) {
            int row = s * 4 + quad;
            if (row0 + row < N_NODES) {
                half8 v = *(const half8*)&stage[wv][row][l16 * 8];
                *(half8*)(Op + (size_t)row * DIM + l16 * 8) = v;
            }
        }
#pragma unroll
        for (int kk = 0; kk < 4; ++kk) aNow[kk] = aNext[kk];
    }
}

// ---------------------------------------------------------------------------
// attend v5 (R25): score via fdot2; row = pr>>3 shared by KA and VM gathers
// (pre-packed by scatter). q[dst] register-resident; online per-rel softmax.
// ---------------------------------------------------------------------------
__global__ __launch_bounds__(256) void attend_kernel(
    const _Float16* __restrict__ KA, const _Float16* __restrict__ qF,
    const _Float16* __restrict__ VMF, const int* __restrict__ dpr,
    const int* __restrict__ doff, const int* __restrict__ dcnt,
    _Float16* __restrict__ aggF) {
    int wv = threadIdx.x >> 6, lane = threadIdx.x & 63;
    int dst = blockIdx.x * 4 + wv;
    if (dst >= N_NODES) return;
    int l16 = lane & 15, g = lane >> 4, l8 = lane & 7;
    int beg = doff[dst], cnt = dcnt[dst];

    // q[dst] fragment: 8 halves per lane, register-resident for the kernel
    half8 qv = *(const half8*)(qF + (size_t)dst * DIM + l16 * 8);
    const half2* q2 = (const half2*)&qv;

    float m_own = -3e38f, sum_own = 0.f;
    float s0 = 0.f, s1 = 0.f, s2 = 0.f;
    int p0 = 0, p1 = 0, p2 = 0;

    // phase 1: scores; park (s, pr); ONLINE per-rel (max, sum) on owning lane
    for (int j0 = 0; j0 < cnt; j0 += 4) {
        int j = j0 + g;
        bool valid = j < cnt;
        int pr = valid ? dpr[beg + j] : 0;
        int rel = pr & 7;
        half8 kv = *(const half8*)(KA + ((size_t)(pr >> 3) << 7) + l16 * 8);
        const half2* k2 = (const half2*)&kv;
        float sa = __builtin_amdgcn_fdot2(k2[0], q2[0], 0.f, false);
        sa = __builtin_amdgcn_fdot2(k2[1], q2[1], sa, false);
        float sb = __builtin_amdgcn_fdot2(k2[2], q2[2], 0.f, false);
        sb = __builtin_amdgcn_fdot2(k2[3], q2[3], sb, false);
        float s = sa + sb;
        s += __shfl_xor(s, 1, 16);
        s += __shfl_xor(s, 2, 16);
        s += __shfl_xor(s, 4, 16);
        s += __shfl_xor(s, 8, 16);
        if (!valid) s = -3e38f;
        int slot = j0 >> 6;            // wave-uniform
        int idx = (j0 >> 2) & 15;      // wave-uniform
        if (l16 == idx) {
            if (slot == 0) { s0 = s; p0 = pr; }
            else if (slot == 1) { s1 = s; p1 = pr; }
            else if (slot == 2) { s2 = s; p2 = pr; }
        }
        if (valid && l8 == rel) {
            if (s > m_own) {
                sum_own *= __expf(m_own - s);  // 0 * exp(-huge) = 0 first time
                m_own = s;
            }
            sum_own += __expf(s - m_own);
        }
    }
    // joint merge of (m, sum) across the 4 groups (exp-rescale combine)
    {
        float m2 = __shfl_xor(m_own, 16, 64);
        float t2 = __shfl_xor(sum_own, 16, 64);
        float mn = fmaxf(m_own, m2);
        sum_own = sum_own * __expf(m_own - mn) + t2 * __expf(m2 - mn);
        m_own = mn;
        m2 = __shfl_xor(m_own, 32, 64);
        t2 = __shfl_xor(sum_own, 32, 64);
        mn = fmaxf(m_own, m2);
        sum_own = sum_own * __expf(m_own - mn) + t2 * __expf(m2 - mn);
        m_own = mn;
    }
    float inv_own = (sum_own > 0.f) ? 1.f / sum_own : 0.f;

    // phase 2: alpha = exp(s - m[rel]) * inv[rel]; acc += alpha * VM[row]
    float acc[8] = {0.f, 0.f, 0.f, 0.f, 0.f, 0.f, 0.f, 0.f};
    for (int j0 = 0; j0 < cnt; j0 += 4) {
        int j = j0 + g;
        bool valid = j < cnt;
        int slot = j0 >> 6;
        int idx = (j0 >> 2) & 15;
        float s;
        int pr;
        if (slot < 3) {
            float sv = (slot == 0) ? s0 : (slot == 1) ? s1 : s2;
            int pv = (slot == 0) ? p0 : (slot == 1) ? p1 : p2;
            s = __shfl(sv, idx, 16);
            pr = __shfl(pv, idx, 16);
        } else {  // overflow fallback: recompute (cnt>192 ~ never at deg~10)
            pr = valid ? dpr[beg + j] : 0;
            half8 kv =
                *(const half8*)(KA + ((size_t)(pr >> 3) << 7) + l16 * 8);
            const half2* k2 = (const half2*)&kv;
            float sa = __builtin_amdgcn_fdot2(k2[0], q2[0], 0.f, false);
            sa = __builtin_amdgcn_fdot2(k2[1], q2[1], sa, false);
            float sb = __builtin_amdgcn_fdot2(k2[2], q2[2], 0.f, false);
            sb = __builtin_amdgcn_fdot2(k2[3], q2[3], sb, false);
            s = sa + sb;
            s += __shfl_xor(s, 1, 16);
            s += __shfl_xor(s, 2, 16);
            s += __shfl_xor(s, 4, 16);
            s += __shfl_xor(s, 8, 16);
        }
        int rel = pr & 7;
        float mr = __shfl(m_own, rel, 8);
        float iv = __shfl(inv_own, rel, 8);
        float alpha = valid ? __expf(s - mr) * iv : 0.f;
        half8 v = *(const half8*)(VMF + ((size_t)(pr >> 3) << 7) + l16 * 8);
#pragma unroll
        for (int i = 0; i < 8; ++i) acc[i] += alpha * (float)v[i];
    }
    // merge acc across the 4 groups (each covers the full 128 dims)
#pragma unroll
    for (int i = 0; i < 8; ++i) {
        acc[i] += __shfl_xor(acc[i], 16, 64);
        acc[i] += __shfl_xor(acc[i], 32, 64);
    }
    if (g == 0) {
        half8 o;
#pragma unroll
        for (int i = 0; i < 8; ++i) o[i] = (_Float16)acc[i];
        *(half8*)(aggF + (size_t)dst * DIM + l16 * 8) = o;
    }
}

// out: 128-node type-uniform chunk MFMA GEMM, fp32 stores with sigmoid gate
__global__ __launch_bounds__(256) void out_kernel(
    const _Float16* __restrict__ aggF, const int* __restrict__ ntype,
    const _Float16* __restrict__ WaT, const float* __restrict__ skip,
    const int* __restrict__ nlist, float* __restrict__ out) {
    __shared__ int nid[128];
    int tid = threadIdx.x;
    if (tid < 128) nid[tid] = nlist[blockIdx.x * 128 + tid];
    __syncthreads();
    if (nid[0] < 0) return;
    int t = ntype[nid[0]];
    float sig = 1.f / (1.f + __expf(-skip[t]));
    int wv = tid >> 6, lane = tid & 63, l16 = lane & 15, quad = lane >> 4;
    int r0 = wv * 32;
    int nA[2];
#pragma unroll
    for (int m = 0; m < 2; ++m) nA[m] = nid[r0 + m * 16 + l16];
    const _Float16* B = WaT + (t << 14);
    f32x4 acc[2][8];
#pragma unroll
    for (int m = 0; m < 2; ++m)
#pragma unroll
        for (int c = 0; c < 8; ++c) acc[m][c] = (f32x4){0.f, 0.f, 0.f, 0.f};
    for (int kk = 0; kk < 4; ++kk) {
        int kb = kk * 32 + quad * 8;
        half8 a[2];
#pragma unroll
        for (int m = 0; m < 2; ++m)
            a[m] = (nA[m] >= 0)
                       ? *(const half8*)(aggF + (size_t)nA[m] * DIM + kb)
                       : (half8){0, 0, 0, 0, 0, 0, 0, 0};
#pragma unroll
        for (int c = 0; c < 8; ++c) {
            half8 b = *(const half8*)(B + (c * 16 + l16) * DIM + kb);
#pragma unroll
            for (int m = 0; m < 2; ++m)
                acc[m][c] = __builtin_amdgcn_mfma_f32_16x16x32_f16(
                    a[m], b, acc[m][c], 0, 0, 0);
        }
    }
#pragma unroll
    for (int m = 0; m < 2; ++m)
#pragma unroll
        for (int c = 0; c < 8; ++c)
#pragma unroll
            for (int rg = 0; rg < 4; ++rg) {
                int node = nid[r0 + m * 16 + quad * 4 + rg];
                if (node >= 0)
                    out[(size_t)node * DIM + c * 16 + l16] =
                        acc[m][c][rg] * sig;
            }
}

extern "C" void kernel_launch(void* const* d_in, const int* in_sizes, int n_in,
                              void* d_out, int out_size, void* d_ws,
                              size_t ws_size, hipStream_t stream) {
    const float* h = (const float*)d_in[0];
    const int* adj = (const int*)d_in[1];
    const int* etype = (const int*)d_in[2];
    const int* ntype = (const int*)d_in[3];
    const float* Wk = (const float*)d_in[6];
    const float* Wq = (const float*)d_in[7];
    const float* Wv = (const float*)d_in[8];
    const float* Wa = (const float*)d_in[9];
    const float* pri = (const float*)d_in[10];
    const float* att = (const float*)d_in[11];
    const float* msg = (const float*)d_in[12];
    const float* skip = (const float*)d_in[13];
    float* out = (float*)d_out;

    int* wsi = (int*)d_ws + OFF_INT;
    _Float16* wsh = (_Float16*)d_ws;
    _Float16* KA = wsh + (size_t)OFF_KA * 2;
    _Float16* hF = wsh + (size_t)OFF_HF * 2;
    _Float16* hLo = wsh + (size_t)OFF_HLO * 2;
    _Float16* VMF = wsh + (size_t)OFF_VM * 2;
    _Float16* kF = wsh + (size_t)OFF_KF * 2;
    _Float16* qF = wsh + (size_t)OFF_QF * 2;
    _Float16* aggF = wsh + (size_t)OFF_AGGF * 2;
    _Float16* vF = wsh + (size_t)OFF_VF * 2;
    _Float16* attT = wsh + (size_t)OFF_ATTT * 2;
    _Float16* msgT = wsh + (size_t)OFF_MSGT * 2;
    _Float16* WvT = wsh + (size_t)OFF_WVT * 2;
    _Float16* WaT = wsh + (size_t)OFF_WAT * 2;
    _Float16* WkHiT = wsh + (size_t)OFF_WKHI * 2;
    _Float16* WkLoT = wsh + (size_t)OFF_WKLO * 2;
    _Float16* WqHiT = wsh + (size_t)OFF_WQHI * 2;
    _Float16* WqLoT = wsh + (size_t)OFF_WQLO * 2;

    init_kernel<<<(100000 + 255) / 256, 256, 0, stream>>>(wsi);
    convert_kernel<<<(RR * DIM * DIM + 255) / 256, 256, 0, stream>>>(
        att, msg, Wv, Wa, attT, msgT, WvT, WaT);
    convert2_kernel<<<(TT * DIM * DIM + 255) / 256, 256, 0, stream>>>(
        Wk, Wq, WkHiT, WkLoT, WqHiT, WqLoT);
    hconv_kernel<<<(N_NODES * DIM / 4 + 255) / 256, 256, 0, stream>>>(h, hF,
                                                                      hLo);
    hist_kernel<<<GRID_E, 256, 0, stream>>>(ntype, adj, wsi);
    offsets_kernel<<<1, 1, 0, stream>>>(wsi);
    scanA_kernel<<<SCAN_BLOCKS, 256, 0, stream>>>(wsi);
    scanB_kernel<<<1, 256, 0, stream>>>(wsi);
    scanC_kernel<<<SCAN_BLOCKS, 256, 0, stream>>>(wsi);
    scatter_kernel<<<GRID_E, 256, 0, stream>>>(ntype, etype, adj, wsi);
    {
        dim3 g(CHUNK_GRID, 2);  // x: 128-node chunks, y: w (k=0, q=1)
        kq_mfma_kernel<<<g, 256, 0, stream>>>(hF, hLo, ntype, WkHiT, WkLoT,
                                              WqHiT, WqLoT, wsi + IO_NLIST,
                                              kF, qF);
    }
    vproj_kernel<<<CHUNK_GRID, 256, 0, stream>>>(hF, ntype, WvT,
                                                 wsi + IO_NLIST, vF);
    // pass 1: KA = pri*rsqrt * (kF @ attT^T); writes over hF region (dead).
    // pass 2: VMF = vF @ msgT^T; writes over kF/hLo/Wsplit regions (dead).
    nr_gemm3_kernel<<<RR * NR3_CHUNKS, 256, 0, stream>>>(kF, attT, KA, pri, 1);
    nr_gemm3_kernel<<<RR * NR3_CHUNKS, 256, 0, stream>>>(vF, msgT, VMF, pri, 0);
    attend_kernel<<<(N_NODES + 3) / 4, 256, 0, stream>>>(
        KA, qF, VMF, wsi + IO_DPR, wsi + IO_DOFF, wsi + IO_DCNT, aggF);
    out_kernel<<<CHUNK_GRID, 256, 0, stream>>>(aggF, ntype, WaT, skip,
                                               wsi + IO_NLIST, out);
}

// Round 15
// 356.044 us; speedup vs baseline: 1.0761x; 1.0051x over previous
//
#include <hip/hip_runtime.h>
#include <math.h>

// ---------------------------------------------------------------------------
// HGT layer slice. R26: attend v6 — 8-lane edge groups (was 16).
// R25 post-mortem: fdot2+addressing was neutral (51->50us): attend's VALU is
// dominated by per-edge bookkeeping REPLICATED across 16 lanes (shuffle
// reduce, park/unpark, rel/mr/iv/alpha) + only 4 edges in flight. FETCH
// 132MB ~= compulsory gather minimum -> memory side done. Fix: 8 groups x
// 8 lanes, 16 dims/lane (2x16B loads, same 256B/edge coalescing): score
// tree 4->3 levels, bookkeeping lanes halved, 8 edges in flight (cnt~10 ->
// 2 iters). Parking isomorphic (idx=(j0>>3)&7 on l8==idx, slot=j0>>6,
// capacity 192); (m,sum) ownership l8==rel unchanged; merges 3 xor levels.
// Same ~1e-7 summation-order perturbation class as R21/R22/R25.
//
// kq v7 LDS-staged f16x2 MFMA (R24), attend v4 factorization (R22), online
// softmax (R21), nr_gemm v6 (R16), parallel scan (R10), [rel][node] (R12).
// ---------------------------------------------------------------------------

#define N_NODES 50000
#define N_EDGES 500000
#define DIM 128
#define TT 8
#define RR 8
#define RSQRT_DK 0.08838834764831845f

#define CHUNK_GRID 399               // 399*128 = 51072 >= 50000 + 8*127
#define NODE_LIST_LEN (CHUNK_GRID * 128)
#define GRID_E ((N_EDGES + 255) / 256)   // 1954, also covers N
#define SCAN_BLOCKS ((N_NODES + 255) / 256)   // 196

// nr_gemm v6 geometry: 112 chunks x 448 rows (7 iters x 64) = 50176 >= 50000
#define NR3_CHUNKS 112
#define NR3_ROWS 448
#define NR3_ITERS 7

// word offsets (4B units); _Float16 index = 2*word
// Lifetime audit (stream order: kq_mfma -> vproj -> nrg1(KA) -> nrg2(VM) ->
// attend -> out):
//   KA  @ 0..25.6M    written by nrg1; hF alias dead after vproj
//   VMF @ 25.6..51.2M written by nrg2; kF/hLo/Wsplit aliases dead by then
//   kF  @ 25.6M       written by kq_mfma, read by nrg1, clobbered by nrg2 OK
//   hLo @ 28.8M       (=VMF[1]) written by hconv, read by kq_mfma, dead
//   Wsplit@48.0-48.3M (=VMF[7]) written by convert2, read by kq_mfma, dead
//   qF  @ 51.2M       written by kq_mfma, read by attend; no aliasing writer
//   aggF@ 54.4M       written by attend, read by out; vF alias dead by then
#define OFF_KA 0                   // kA f16 [rel][n][128]
#define OFF_HF 0                   // alias: hF16 = hHi (dead before KA write)
#define OFF_VM 25600000            // VMF16 [rel][n][128]
#define OFF_KF 25600000            // alias: kF16 (dead before VM write)
#define OFF_HLO 28800000           // hLo f16 [n][128] (=VMF[1] region)
#define OFF_WKHI 48000000          // W f16x2 splits, [t][f][d], 100k spacing
#define OFF_WKLO 48100000          //   (=VMF[7] region, dead before nrg2)
#define OFF_WQHI 48200000
#define OFF_WQLO 48300000
#define OFF_QF 51200000            // qF16 — no aliasing writer after kq
#define OFF_AGGF 54400000
#define OFF_VF 54400000            // alias: vF16 (dead before attend writes agg)
#define OFF_ATTT 57600000          // attT [r][f][d] (transposed), 100k spacing
#define OFF_MSGT 57700000
#define OFF_WVT 57800000
#define OFF_WAT 57900000
#define OFF_INT 58000000           // int region, +701,872 -> 58,701,872 words
#define IO_NLIST 0                 // 51,072
#define IO_CNT_N 51072
#define IO_CUR_N 51080
#define IO_POFF_N 51088
#define IO_DCNT 51104              // 50,000
#define IO_DCUR 101104             // 50,000
#define IO_DOFF 151104             // 50,000
#define IO_DPR 201104              // 500,000 packed ((rel*N+src)*8|rel)
#define IO_BLKSUM 701104           // 256 per-scan-block totals
#define IO_BLKOFF 701360           // 256 scanned block offsets; end 701,616

typedef _Float16 half8 __attribute__((ext_vector_type(8)));
typedef _Float16 half4 __attribute__((ext_vector_type(4)));
typedef _Float16 half2 __attribute__((ext_vector_type(2)));
typedef float f32x4 __attribute__((ext_vector_type(4)));

__global__ void init_kernel(int* wsi) {
    int i = blockIdx.x * blockDim.x + threadIdx.x;
    if (i < NODE_LIST_LEN) wsi[IO_NLIST + i] = -1;
    if (i < 32) wsi[IO_CNT_N + i] = 0;
    if (i < 100000) wsi[IO_DCNT + i] = 0;  // dcnt + dcur contiguous
}

// weight tensors transposed to [.][f][d] f16
__global__ void convert_kernel(const float* __restrict__ att,
                               const float* __restrict__ msg,
                               const float* __restrict__ Wv,
                               const float* __restrict__ Wa,
                               _Float16* __restrict__ attT,
                               _Float16* __restrict__ msgT,
                               _Float16* __restrict__ WvT,
                               _Float16* __restrict__ WaT) {
    int i = blockIdx.x * 256 + threadIdx.x;
    if (i >= RR * DIM * DIM) return;
    int td = i >> 14, d = (i >> 7) & 127, f = i & 127;
    int tr = (td << 14) + (f << 7) + d;
    attT[tr] = (_Float16)att[i];
    msgT[tr] = (_Float16)msg[i];
    WvT[tr] = (_Float16)Wv[i];
    WaT[tr] = (_Float16)Wa[i];
}

// f16x2 split of Wk, Wq (transposed [t][f][d]): hi = f16(x), lo = f16(x-hi)
__global__ void convert2_kernel(const float* __restrict__ Wk,
                                const float* __restrict__ Wq,
                                _Float16* __restrict__ WkHiT,
                                _Float16* __restrict__ WkLoT,
                                _Float16* __restrict__ WqHiT,
                                _Float16* __restrict__ WqLoT) {
    int i = blockIdx.x * 256 + threadIdx.x;
    if (i >= TT * DIM * DIM) return;
    int td = i >> 14, d = (i >> 7) & 127, f = i & 127;
    int tr = (td << 14) + (f << 7) + d;
    float xk = Wk[i];
    _Float16 hk = (_Float16)xk;
    WkHiT[tr] = hk;
    WkLoT[tr] = (_Float16)(xk - (float)hk);  // Sterbenz: exact subtraction
    float xq = Wq[i];
    _Float16 hq = (_Float16)xq;
    WqHiT[tr] = hq;
    WqLoT[tr] = (_Float16)(xq - (float)hq);
}

// h -> hF (hi) + hLo (residual), both f16
__global__ void hconv_kernel(const float* __restrict__ h,
                             _Float16* __restrict__ hF,
                             _Float16* __restrict__ hLo) {
    int i = blockIdx.x * 256 + threadIdx.x;
    if (i < N_NODES * DIM / 4) {
        float4 v = ((const float4*)h)[i];
        half4 o, r;
        o[0] = (_Float16)v.x; o[1] = (_Float16)v.y;
        o[2] = (_Float16)v.z; o[3] = (_Float16)v.w;
        r[0] = (_Float16)(v.x - (float)o[0]);
        r[1] = (_Float16)(v.y - (float)o[1]);
        r[2] = (_Float16)(v.z - (float)o[2]);
        r[3] = (_Float16)(v.w - (float)o[3]);
        *(half4*)(hF + (size_t)i * 4) = o;
        *(half4*)(hLo + (size_t)i * 4) = r;
    }
}

__global__ void hist_kernel(const int* __restrict__ ntype,
                            const int* __restrict__ adj, int* wsi) {
    __shared__ int cn[TT];
    int tid = threadIdx.x;
    if (tid < TT) cn[tid] = 0;
    __syncthreads();
    int i = blockIdx.x * blockDim.x + tid;
    if (i < N_NODES) atomicAdd(&cn[ntype[i]], 1);
    if (i < N_EDGES) atomicAdd(&wsi[IO_DCNT + adj[N_EDGES + i]], 1);
    __syncthreads();
    if (tid < TT && cn[tid] > 0) atomicAdd(&wsi[IO_CNT_N + tid], cn[tid]);
}

__global__ void offsets_kernel(int* wsi) {
    int off = 0;
    for (int t = 0; t < TT; ++t) {
        wsi[IO_POFF_N + t] = off;
        off += ((wsi[IO_CNT_N + t] + 127) >> 7) << 7;  // pad to 128
    }
}

// 3-phase parallel exclusive scan of the 50k dst counts
__global__ __launch_bounds__(256) void scanA_kernel(int* wsi) {
    __shared__ int tmp[256];
    int tid = threadIdx.x;
    int i = blockIdx.x * 256 + tid;
    int v = (i < N_NODES) ? wsi[IO_DCNT + i] : 0;
    tmp[tid] = v;
    __syncthreads();
    for (int off = 1; off < 256; off <<= 1) {
        int t = (tid >= off) ? tmp[tid - off] : 0;
        __syncthreads();
        tmp[tid] += t;
        __syncthreads();
    }
    if (i < N_NODES) wsi[IO_DOFF + i] = tmp[tid] - v;  // block-local exclusive
    if (tid == 255) wsi[IO_BLKSUM + blockIdx.x] = tmp[255];
}

__global__ __launch_bounds__(256) void scanB_kernel(int* wsi) {
    __shared__ int tmp[256];
    int tid = threadIdx.x;
    int v = (tid < SCAN_BLOCKS) ? wsi[IO_BLKSUM + tid] : 0;
    tmp[tid] = v;
    __syncthreads();
    for (int off = 1; off < 256; off <<= 1) {
        int t = (tid >= off) ? tmp[tid - off] : 0;
        __syncthreads();
        tmp[tid] += t;
        __syncthreads();
    }
    wsi[IO_BLKOFF + tid] = tmp[tid] - v;
}

__global__ __launch_bounds__(256) void scanC_kernel(int* wsi) {
    int i = blockIdx.x * 256 + threadIdx.x;
    if (i < N_NODES) wsi[IO_DOFF + i] += wsi[IO_BLKOFF + blockIdx.x];
}

// dpr pack: ((rel*N_NODES+src) << 3) | rel  — row index for KA/VM gathers
__global__ void scatter_kernel(const int* __restrict__ ntype,
                               const int* __restrict__ etype,
                               const int* __restrict__ adj, int* wsi) {
    __shared__ int cn[TT], bn[TT];
    int tid = threadIdx.x;
    if (tid < TT) cn[tid] = 0;
    __syncthreads();
    int i = blockIdx.x * blockDim.x + tid;
    int t = -1, rnk = 0;
    if (i < N_NODES) {
        t = ntype[i];
        rnk = atomicAdd(&cn[t], 1);
    }
    __syncthreads();
    if (tid < TT && cn[tid] > 0) bn[tid] = atomicAdd(&wsi[IO_CUR_N + tid], cn[tid]);
    __syncthreads();
    if (t >= 0)
        wsi[IO_NLIST + wsi[IO_POFF_N + t] + bn[t] + rnk] = i;
    if (i < N_EDGES) {
        int d = adj[N_EDGES + i];
        int pos = wsi[IO_DOFF + d] + atomicAdd(&wsi[IO_DCUR + d], 1);
        int rel = etype[i];
        wsi[IO_DPR + pos] = ((rel * N_NODES + adj[i]) << 3) | rel;
    }
}

// ---------------------------------------------------------------------------
// kq v7 (R24-proven): f16x2-split MFMA with B staged in LDS.
// ---------------------------------------------------------------------------
__global__ __launch_bounds__(256, 2) void kq_mfma_kernel(
    const _Float16* __restrict__ hHi, const _Float16* __restrict__ hLo,
    const int* __restrict__ ntype,
    const _Float16* __restrict__ WkHiT, const _Float16* __restrict__ WkLoT,
    const _Float16* __restrict__ WqHiT, const _Float16* __restrict__ WqLoT,
    const int* __restrict__ nlist, _Float16* __restrict__ kout,
    _Float16* __restrict__ qout) {
    __shared__ _Float16 bHiS[128][136];
    __shared__ _Float16 bLoS[128][136];
    __shared__ int nid[128];
    int tid = threadIdx.x;
    if (tid < 128) nid[tid] = nlist[blockIdx.x * 128 + tid];
    __syncthreads();
    if (nid[0] < 0) return;
    int t = ntype[nid[0]];
    int w = blockIdx.y;
    const _Float16* BHi = (w ? WqHiT : WkHiT) + (t << 14);
    const _Float16* BLo = (w ? WqLoT : WkLoT) + (t << 14);
    for (int i = tid; i < 2048; i += 256) {
        int row = i >> 4, col = (i & 15) * 8;
        *(half8*)&bHiS[row][col] = *(const half8*)(BHi + row * DIM + col);
        *(half8*)&bLoS[row][col] = *(const half8*)(BLo + row * DIM + col);
    }
    __syncthreads();

    int wv = tid >> 6, lane = tid & 63, l16 = lane & 15, quad = lane >> 4;
    int r0 = wv * 32;
    int nA[2];
#pragma unroll
    for (int m = 0; m < 2; ++m) nA[m] = nid[r0 + m * 16 + l16];
    _Float16* O = w ? qout : kout;
    f32x4 acc[2][8];
#pragma unroll
    for (int m = 0; m < 2; ++m)
#pragma unroll
        for (int c = 0; c < 8; ++c) acc[m][c] = (f32x4){0.f, 0.f, 0.f, 0.f};
    for (int kk = 0; kk < 4; ++kk) {
        int kb = kk * 32 + quad * 8;
        half8 aHi[2], aLo[2];
#pragma unroll
        for (int m = 0; m < 2; ++m) {
            aHi[m] = (nA[m] >= 0)
                         ? *(const half8*)(hHi + (size_t)nA[m] * DIM + kb)
                         : (half8){0, 0, 0, 0, 0, 0, 0, 0};
            aLo[m] = (nA[m] >= 0)
                         ? *(const half8*)(hLo + (size_t)nA[m] * DIM + kb)
                         : (half8){0, 0, 0, 0, 0, 0, 0, 0};
        }
#pragma unroll
        for (int c = 0; c < 8; ++c) {
            half8 bHi = *(const half8*)&bHiS[c * 16 + l16][kb];
            half8 bLo = *(const half8*)&bLoS[c * 16 + l16][kb];
#pragma unroll
            for (int m = 0; m < 2; ++m) {
                acc[m][c] = __builtin_amdgcn_mfma_f32_16x16x32_f16(
                    aHi[m], bHi, acc[m][c], 0, 0, 0);
                acc[m][c] = __builtin_amdgcn_mfma_f32_16x16x32_f16(
                    aHi[m], bLo, acc[m][c], 0, 0, 0);
                acc[m][c] = __builtin_amdgcn_mfma_f32_16x16x32_f16(
                    aLo[m], bHi, acc[m][c], 0, 0, 0);
            }
        }
    }
#pragma unroll
    for (int m = 0; m < 2; ++m)
#pragma unroll
        for (int c = 0; c < 8; ++c)
#pragma unroll
            for (int rg = 0; rg < 4; ++rg) {
                int node = nid[r0 + m * 16 + quad * 4 + rg];
                if (node >= 0)
                    O[(size_t)node * DIM + c * 16 + l16] =
                        (_Float16)acc[m][c][rg];
            }
}

// v: 128-node type-uniform chunk MFMA GEMM (value path: f16-tolerant)
__global__ __launch_bounds__(256) void vproj_kernel(
    const _Float16* __restrict__ hF, const int* __restrict__ ntype,
    const _Float16* __restrict__ WvT, const int* __restrict__ nlist,
    _Float16* __restrict__ vout) {
    __shared__ int nid[128];
    int tid = threadIdx.x;
    if (tid < 128) nid[tid] = nlist[blockIdx.x * 128 + tid];
    __syncthreads();
    if (nid[0] < 0) return;
    int t = ntype[nid[0]];
    int wv = tid >> 6, lane = tid & 63, l16 = lane & 15, quad = lane >> 4;
    int r0 = wv * 32;
    int nA[2];
#pragma unroll
    for (int m = 0; m < 2; ++m) nA[m] = nid[r0 + m * 16 + l16];
    const _Float16* B = WvT + (t << 14);
    f32x4 acc[2][8];
#pragma unroll
    for (int m = 0; m < 2; ++m)
#pragma unroll
        for (int c = 0; c < 8; ++c) acc[m][c] = (f32x4){0.f, 0.f, 0.f, 0.f};
    for (int kk = 0; kk < 4; ++kk) {
        int kb = kk * 32 + quad * 8;
        half8 a[2];
#pragma unroll
        for (int m = 0; m < 2; ++m)
            a[m] = (nA[m] >= 0)
                       ? *(const half8*)(hF + (size_t)nA[m] * DIM + kb)
                       : (half8){0, 0, 0, 0, 0, 0, 0, 0};
#pragma unroll
        for (int c = 0; c < 8; ++c) {
            half8 b = *(const half8*)(B + (c * 16 + l16) * DIM + kb);
#pragma unroll
            for (int m = 0; m < 2; ++m)
                acc[m][c] = __builtin_amdgcn_mfma_f32_16x16x32_f16(
                    a[m], b, acc[m][c], 0, 0, 0);
        }
    }
#pragma unroll
    for (int m = 0; m < 2; ++m)
#pragma unroll
        for (int c = 0; c < 8; ++c)
#pragma unroll
            for (int rg = 0; rg < 4; ++rg) {
                int node = nid[r0 + m * 16 + quad * 4 + rg];
                if (node >= 0)
                    vout[(size_t)node * DIM + c * 16 + l16] =
                        (_Float16)acc[m][c][rg];
            }
}

// ---------------------------------------------------------------------------
// nr_gemm v6 (R16-proven): one block = one rel; B register-resident; stream
// NR3_ITERS x 64-row tiles with double-buffered A prefetch.
// ---------------------------------------------------------------------------
__global__ __launch_bounds__(256, 2) void nr_gemm3_kernel(
    const _Float16* __restrict__ A, const _Float16* __restrict__ B8,
    _Float16* __restrict__ Out, const float* __restrict__ pri, int isU) {
    __shared__ _Float16 stage[4][16][136];
    int bid = blockIdx.x;
    int rel = bid / NR3_CHUNKS;
    int chunk = bid - rel * NR3_CHUNKS;
    float scale = isU ? pri[rel] * RSQRT_DK : 1.0f;
    const _Float16* Bb = B8 + (rel << 14);
    int tid = threadIdx.x;
    int wv = tid >> 6, lane = tid & 63;
    int l16 = lane & 15, quad = lane >> 4;

    half8 bfrag[8][4];
#pragma unroll
    for (int c = 0; c < 8; ++c)
#pragma unroll
        for (int kk = 0; kk < 4; ++kk)
            bfrag[c][kk] =
                *(const half8*)(Bb + (c * 16 + l16) * DIM + kk * 32 + quad * 8);

    _Float16* Orel = Out + (size_t)rel * N_NODES * DIM;
    int base = chunk * NR3_ROWS + wv * 16;  // this wave's first tile row

    half8 aNow[4], aNext[4];
    {
        int nodeA = base + l16;
#pragma unroll
        for (int kk = 0; kk < 4; ++kk)
            aNow[kk] = (nodeA < N_NODES)
                           ? *(const half8*)(A + (size_t)nodeA * DIM +
                                             kk * 32 + quad * 8)
                           : (half8){0, 0, 0, 0, 0, 0, 0, 0};
    }

    for (int it = 0; it < NR3_ITERS; ++it) {
        int row0 = base + it * 64;
        if (it + 1 < NR3_ITERS) {
            int nodeA = row0 + 64 + l16;
#pragma unroll
            for (int kk = 0; kk < 4; ++kk)
                aNext[kk] = (nodeA < N_NODES)
                                ? *(const half8*)(A + (size_t)nodeA * DIM +
                                                  kk * 32 + quad * 8)
                                : (half8){0, 0, 0, 0, 0, 0, 0, 0};
        }
        f32x4 acc[8];
#pragma unroll
        for (int c = 0; c < 8; ++c) acc[c] = (f32x4){0.f, 0.f, 0.f, 0.f};
#pragma unroll
        for (int kk = 0; kk < 4; ++kk)
#pragma unroll
            for (int c = 0; c < 8; ++c)
                acc[c] = __builtin_amdgcn_mfma_f32_16x16x32_f16(
                    bfrag[c][kk], aNow[kk], acc[c], 0, 0, 0);
#pragma unroll
        for (int c = 0; c < 8; ++c) {
            half4 o;
#pragma unroll
            for (int rg = 0; rg < 4; ++rg)
                o[rg] = (_Float16)(acc[c][rg] * scale);
            *(half4*)&stage[wv][l16][c * 16 + quad * 4] = o;
        }
        _Float16* Op = Orel + (size_t)row0 * DIM;
#pragma unroll
        for (int s = 0; s < 4; ++s) {
            int row = s * 4 + quad;
            if (row0 + row < N_NODES) {
                half8 v = *(const half8*)&stage[wv][row][l16 * 8];
                *(half8*)(Op + (size_t)row * DIM + l16 * 8) = v;
            }
        }
#pragma unroll
        for (int kk = 0; kk < 4; ++kk) aNow[kk] = aNext[kk];
    }
}

// ---------------------------------------------------------------------------
// attend v6 (R26): 8 groups x 8 lanes; 16 dims/lane (2x half8). Parking:
// idx=(j0>>3)&7 on l8==idx, slot=j0>>6 (192-edge capacity + fallback).
// Online per-rel softmax on lane l8==rel; 3-level xor merges (8,16,32).
// ---------------------------------------------------------------------------
__global__ __launch_bounds__(256) void attend_kernel(
    const _Float16* __restrict__ KA, const _Float16* __restrict__ qF,
    const _Float16* __restrict__ VMF, const int* __restrict__ dpr,
    const int* __restrict__ doff, const int* __restrict__ dcnt,
    _Float16* __restrict__ aggF) {
    int wv = threadIdx.x >> 6, lane = threadIdx.x & 63;
    int dst = blockIdx.x * 4 + wv;
    if (dst >= N_NODES) return;
    int l8 = lane & 7, g = lane >> 3;   // 8 groups of 8 lanes
    int beg = doff[dst], cnt = dcnt[dst];

    // q[dst]: 16 halves per lane (dims l8*16 .. +15)
    half8 qv0 = *(const half8*)(qF + (size_t)dst * DIM + l8 * 16);
    half8 qv1 = *(const half8*)(qF + (size_t)dst * DIM + l8 * 16 + 8);
    const half2* q20 = (const half2*)&qv0;
    const half2* q21 = (const half2*)&qv1;

    float m_own = -3e38f, sum_own = 0.f;
    float s0 = 0.f, s1 = 0.f, s2 = 0.f;
    int p0 = 0, p1 = 0, p2 = 0;

    // phase 1: scores; park (s, pr); ONLINE per-rel (max, sum) on owning lane
    for (int j0 = 0; j0 < cnt; j0 += 8) {
        int j = j0 + g;
        bool valid = j < cnt;
        int pr = valid ? dpr[beg + j] : 0;
        int rel = pr & 7;
        const _Float16* kr = KA + ((size_t)(pr >> 3) << 7) + l8 * 16;
        half8 kv0 = *(const half8*)kr;
        half8 kv1 = *(const half8*)(kr + 8);
        const half2* k20 = (const half2*)&kv0;
        const half2* k21 = (const half2*)&kv1;
        float sa = __builtin_amdgcn_fdot2(k20[0], q20[0], 0.f, false);
        sa = __builtin_amdgcn_fdot2(k20[1], q20[1], sa, false);
        sa = __builtin_amdgcn_fdot2(k20[2], q20[2], sa, false);
        sa = __builtin_amdgcn_fdot2(k20[3], q20[3], sa, false);
        float sb = __builtin_amdgcn_fdot2(k21[0], q21[0], 0.f, false);
        sb = __builtin_amdgcn_fdot2(k21[1], q21[1], sb, false);
        sb = __builtin_amdgcn_fdot2(k21[2], q21[2], sb, false);
        sb = __builtin_amdgcn_fdot2(k21[3], q21[3], sb, false);
        float s = sa + sb;
        s += __shfl_xor(s, 1, 8);
        s += __shfl_xor(s, 2, 8);
        s += __shfl_xor(s, 4, 8);
        if (!valid) s = -3e38f;
        int slot = j0 >> 6;            // wave-uniform
        int idx = (j0 >> 3) & 7;       // wave-uniform
        if (l8 == idx) {
            if (slot == 0) { s0 = s; p0 = pr; }
            else if (slot == 1) { s1 = s; p1 = pr; }
            else if (slot == 2) { s2 = s; p2 = pr; }
        }
        if (valid && l8 == rel) {
            if (s > m_own) {
                sum_own *= __expf(m_own - s);  // 0 * exp(-huge) = 0 first time
                m_own = s;
            }
            sum_own += __expf(s - m_own);
        }
    }
    // joint merge of (m, sum) across the 8 groups (exp-rescale combine)
#pragma unroll
    for (int d = 8; d <= 32; d <<= 1) {
        float m2 = __shfl_xor(m_own, d, 64);
        float t2 = __shfl_xor(sum_own, d, 64);
        float mn = fmaxf(m_own, m2);
        sum_own = sum_own * __expf(m_own - mn) + t2 * __expf(m2 - mn);
        m_own = mn;
    }
    float inv_own = (sum_own > 0.f) ? 1.f / sum_own : 0.f;

    // phase 2: alpha = exp(s - m[rel]) * inv[rel]; acc += alpha * VM[row]
    float acc[16];
#pragma unroll
    for (int i = 0; i < 16; ++i) acc[i] = 0.f;
    for (int j0 = 0; j0 < cnt; j0 += 8) {
        int j = j0 + g;
        bool valid = j < cnt;
        int slot = j0 >> 6;
        int idx = (j0 >> 3) & 7;
        float s;
        int pr;
        if (slot < 3) {
            float sv = (slot == 0) ? s0 : (slot == 1) ? s1 : s2;
            int pv = (slot == 0) ? p0 : (slot == 1) ? p1 : p2;
            s = __shfl(sv, idx, 8);
            pr = __shfl(pv, idx, 8);
        } else {  // overflow fallback: recompute (cnt>192 ~ never at deg~10)
            pr = valid ? dpr[beg + j] : 0;
            const _Float16* kr = KA + ((size_t)(pr >> 3) << 7) + l8 * 16;
            half8 kv0 = *(const half8*)kr;
            half8 kv1 = *(const half8*)(kr + 8);
            const half2* k20 = (const half2*)&kv0;
            const half2* k21 = (const half2*)&kv1;
            float sa = __builtin_amdgcn_fdot2(k20[0], q20[0], 0.f, false);
            sa = __builtin_amdgcn_fdot2(k20[1], q20[1], sa, false);
            sa = __builtin_amdgcn_fdot2(k20[2], q20[2], sa, false);
            sa = __builtin_amdgcn_fdot2(k20[3], q20[3], sa, false);
            float sb = __builtin_amdgcn_fdot2(k21[0], q21[0], 0.f, false);
            sb = __builtin_amdgcn_fdot2(k21[1], q21[1], sb, false);
            sb = __builtin_amdgcn_fdot2(k21[2], q21[2], sb, false);
            sb = __builtin_amdgcn_fdot2(k21[3], q21[3], sb, false);
            s = sa + sb;
            s += __shfl_xor(s, 1, 8);
            s += __shfl_xor(s, 2, 8);
            s += __shfl_xor(s, 4, 8);
        }
        int rel = pr & 7;
        float mr = __shfl(m_own, rel, 8);
        float iv = __shfl(inv_own, rel, 8);
        float alpha = valid ? __expf(s - mr) * iv : 0.f;
        const _Float16* vr = VMF + ((size_t)(pr >> 3) << 7) + l8 * 16;
        half8 v0 = *(const half8*)vr;
        half8 v1 = *(const half8*)(vr + 8);
#pragma unroll
        for (int i = 0; i < 8; ++i) acc[i] += alpha * (float)v0[i];
#pragma unroll
        for (int i = 0; i < 8; ++i) acc[8 + i] += alpha * (float)v1[i];
    }
    // merge acc across the 8 groups (same l8 -> same dims; xor 8/16/32)
#pragma unroll
    for (int i = 0; i < 16; ++i) {
        acc[i] += __shfl_xor(acc[i], 8, 64);
        acc[i] += __shfl_xor(acc[i], 16, 64);
        acc[i] += __shfl_xor(acc[i], 32, 64);
    }
    if (g == 0) {
        half8 o0, o1;
#pragma unroll
        for (int i = 0; i < 8; ++i) {
            o0[i] = (_Float16)acc[i];
            o1[i] = (_Float16)acc[8 + i];
        }
        _Float16* op = aggF + (size_t)dst * DIM + l8 * 16;
        *(half8*)op = o0;
        *(half8*)(op + 8) = o1;
    }
}

// out: 128-node type-uniform chunk MFMA GEMM, fp32 stores with sigmoid gate
__global__ __launch_bounds__(256) void out_kernel(
    const _Float16* __restrict__ aggF, const int* __restrict__ ntype,
    const _Float16* __restrict__ WaT, const float* __restrict__ skip,
    const int* __restrict__ nlist, float* __restrict__ out) {
    __shared__ int nid[128];
    int tid = threadIdx.x;
    if (tid < 128) nid[tid] = nlist[blockIdx.x * 128 + tid];
    __syncthreads();
    if (nid[0] < 0) return;
    int t = ntype[nid[0]];
    float sig = 1.f / (1.f + __expf(-skip[t]));
    int wv = tid >> 6, lane = tid & 63, l16 = lane & 15, quad = lane >> 4;
    int r0 = wv * 32;
    int nA[2];
#pragma unroll
    for (int m = 0; m < 2; ++m) nA[m] = nid[r0 + m * 16 + l16];
    const _Float16* B = WaT + (t << 14);
    f32x4 acc[2][8];
#pragma unroll
    for (int m = 0; m < 2; ++m)
#pragma unroll
        for (int c = 0; c < 8; ++c) acc[m][c] = (f32x4){0.f, 0.f, 0.f, 0.f};
    for (int kk = 0; kk < 4; ++kk) {
        int kb = kk * 32 + quad * 8;
        half8 a[2];
#pragma unroll
        for (int m = 0; m < 2; ++m)
            a[m] = (nA[m] >= 0)
                       ? *(const half8*)(aggF + (size_t)nA[m] * DIM + kb)
                       : (half8){0, 0, 0, 0, 0, 0, 0, 0};
#pragma unroll
        for (int c = 0; c < 8; ++c) {
            half8 b = *(const half8*)(B + (c * 16 + l16) * DIM + kb);
#pragma unroll
            for (int m = 0; m < 2; ++m)
                acc[m][c] = __builtin_amdgcn_mfma_f32_16x16x32_f16(
                    a[m], b, acc[m][c], 0, 0, 0);
        }
    }
#pragma unroll
    for (int m = 0; m < 2; ++m)
#pragma unroll
        for (int c = 0; c < 8; ++c)
#pragma unroll
            for (int rg = 0; rg < 4; ++rg) {
                int node = nid[r0 + m * 16 + quad * 4 + rg];
                if (node >= 0)
                    out[(size_t)node * DIM + c * 16 + l16] =
                        acc[m][c][rg] * sig;
            }
}

extern "C" void kernel_launch(void* const* d_in, const int* in_sizes, int n_in,
                              void* d_out, int out_size, void* d_ws,
                              size_t ws_size, hipStream_t stream) {
    const float* h = (const float*)d_in[0];
    const int* adj = (const int*)d_in[1];
    const int* etype = (const int*)d_in[2];
    const int* ntype = (const int*)d_in[3];
    const float* Wk = (const float*)d_in[6];
    const float* Wq = (const float*)d_in[7];
    const float* Wv = (const float*)d_in[8];
    const float* Wa = (const float*)d_in[9];
    const float* pri = (const float*)d_in[10];
    const float* att = (const float*)d_in[11];
    const float* msg = (const float*)d_in[12];
    const float* skip = (const float*)d_in[13];
    float* out = (float*)d_out;

    int* wsi = (int*)d_ws + OFF_INT;
    _Float16* wsh = (_Float16*)d_ws;
    _Float16* KA = wsh + (size_t)OFF_KA * 2;
    _Float16* hF = wsh + (size_t)OFF_HF * 2;
    _Float16* hLo = wsh + (size_t)OFF_HLO * 2;
    _Float16* VMF = wsh + (size_t)OFF_VM * 2;
    _Float16* kF = wsh + (size_t)OFF_KF * 2;
    _Float16* qF = wsh + (size_t)OFF_QF * 2;
    _Float16* aggF = wsh + (size_t)OFF_AGGF * 2;
    _Float16* vF = wsh + (size_t)OFF_VF * 2;
    _Float16* attT = wsh + (size_t)OFF_ATTT * 2;
    _Float16* msgT = wsh + (size_t)OFF_MSGT * 2;
    _Float16* WvT = wsh + (size_t)OFF_WVT * 2;
    _Float16* WaT = wsh + (size_t)OFF_WAT * 2;
    _Float16* WkHiT = wsh + (size_t)OFF_WKHI * 2;
    _Float16* WkLoT = wsh + (size_t)OFF_WKLO * 2;
    _Float16* WqHiT = wsh + (size_t)OFF_WQHI * 2;
    _Float16* WqLoT = wsh + (size_t)OFF_WQLO * 2;

    init_kernel<<<(100000 + 255) / 256, 256, 0, stream>>>(wsi);
    convert_kernel<<<(RR * DIM * DIM + 255) / 256, 256, 0, stream>>>(
        att, msg, Wv, Wa, attT, msgT, WvT, WaT);
    convert2_kernel<<<(TT * DIM * DIM + 255) / 256, 256, 0, stream>>>(
        Wk, Wq, WkHiT, WkLoT, WqHiT, WqLoT);
    hconv_kernel<<<(N_NODES * DIM / 4 + 255) / 256, 256, 0, stream>>>(h, hF,
                                                                      hLo);
    hist_kernel<<<GRID_E, 256, 0, stream>>>(ntype, adj, wsi);
    offsets_kernel<<<1, 1, 0, stream>>>(wsi);
    scanA_kernel<<<SCAN_BLOCKS, 256, 0, stream>>>(wsi);
    scanB_kernel<<<1, 256, 0, stream>>>(wsi);
    scanC_kernel<<<SCAN_BLOCKS, 256, 0, stream>>>(wsi);
    scatter_kernel<<<GRID_E, 256, 0, stream>>>(ntype, etype, adj, wsi);
    {
        dim3 g(CHUNK_GRID, 2);  // x: 128-node chunks, y: w (k=0, q=1)
        kq_mfma_kernel<<<g, 256, 0, stream>>>(hF, hLo, ntype, WkHiT, WkLoT,
                                              WqHiT, WqLoT, wsi + IO_NLIST,
                                              kF, qF);
    }
    vproj_kernel<<<CHUNK_GRID, 256, 0, stream>>>(hF, ntype, WvT,
                                                 wsi + IO_NLIST, vF);
    // pass 1: KA = pri*rsqrt * (kF @ attT^T); writes over hF region (dead).
    // pass 2: VMF = vF @ msgT^T; writes over kF/hLo/Wsplit regions (dead).
    nr_gemm3_kernel<<<RR * NR3_CHUNKS, 256, 0, stream>>>(kF, attT, KA, pri, 1);
    nr_gemm3_kernel<<<RR * NR3_CHUNKS, 256, 0, stream>>>(vF, msgT, VMF, pri, 0);
    attend_kernel<<<(N_NODES + 3) / 4, 256, 0, stream>>>(
        KA, qF, VMF, wsi + IO_DPR, wsi + IO_DOFF, wsi + IO_DCNT, aggF);
    out_kernel<<<CHUNK_GRID, 256, 0, stream>>>(aggF, ntype, WaT, skip,
                                               wsi + IO_NLIST, out);
}